// Round 5
// baseline (202.410 us; speedup 1.0000x reference)
//
#include <hip/hip_runtime.h>
#include <hip/hip_bf16.h>
#include <cstdint>

#define NH 8
#define DM 512
#define DH 64
#define NB 4
#define SL 1024

typedef __attribute__((ext_vector_type(8))) short bf16x8;
typedef __attribute__((ext_vector_type(4))) float f32x4;
typedef __attribute__((ext_vector_type(4))) unsigned int u32x4;

static __device__ __forceinline__ float bf2f(short s) {
  union { unsigned int u; float f; } c;
  c.u = ((unsigned int)(unsigned short)s) << 16;
  return c.f;
}
static __device__ __forceinline__ unsigned short f2bfbits(float f) {
  union { float f; unsigned int u; } c; c.f = f;
  unsigned int lsb = (c.u >> 16) & 1u;
  unsigned int r = c.u + 0x7fffu + lsb;   // RNE (inputs are finite/normal)
  return (unsigned short)(r >> 16);
}

// ---------- 1) fp32 -> bf16 for q,k,v (each [4096,512]) ----------
__global__ __launch_bounds__(256) void k_cvt_act(
    const float* __restrict__ q, const float* __restrict__ k, const float* __restrict__ v,
    ushort* __restrict__ qb, ushort* __restrict__ kb, ushort* __restrict__ vb) {
  int i = blockIdx.x * 256 + threadIdx.x;   // float4 group, 524288 total
  {
    float4 f = ((const float4*)q)[i];
    ushort4 r = { f2bfbits(f.x), f2bfbits(f.y), f2bfbits(f.z), f2bfbits(f.w) };
    *(ushort4*)(qb + 4 * i) = r;
  }
  {
    float4 f = ((const float4*)k)[i];
    ushort4 r = { f2bfbits(f.x), f2bfbits(f.y), f2bfbits(f.z), f2bfbits(f.w) };
    *(ushort4*)(kb + 4 * i) = r;
  }
  {
    float4 f = ((const float4*)v)[i];
    ushort4 r = { f2bfbits(f.x), f2bfbits(f.y), f2bfbits(f.z), f2bfbits(f.w) };
    *(ushort4*)(vb + 4 * i) = r;
  }
}

// ---------- 2) transpose-convert W [512,512] -> W^T bf16 ----------
__global__ __launch_bounds__(256) void k_cvt_wT(
    const float* __restrict__ w0, const float* __restrict__ w1, const float* __restrict__ w2,
    ushort* __restrict__ o0, ushort* __restrict__ o1, ushort* __restrict__ o2) {
  __shared__ ushort tile[64][65];
  const float* src = blockIdx.z == 0 ? w0 : (blockIdx.z == 1 ? w1 : w2);
  ushort* dst = blockIdx.z == 0 ? o0 : (blockIdx.z == 1 ? o1 : o2);
  int k0 = blockIdx.x * 64, n0 = blockIdx.y * 64;
  int t = threadIdx.x;
  #pragma unroll
  for (int i = 0; i < 16; ++i) {
    int lin = t + i * 256, r = lin >> 6, c = lin & 63;
    tile[r][c] = f2bfbits(src[(size_t)(k0 + r) * DM + n0 + c]);
  }
  __syncthreads();
  #pragma unroll
  for (int i = 0; i < 16; ++i) {
    int lin = t + i * 256, r = lin >> 6, c = lin & 63;
    dst[(size_t)(n0 + r) * DM + k0 + c] = tile[c][r];
  }
}

// ---------- 3) w_fc [64,512] -> bf16 ----------
__global__ __launch_bounds__(256) void k_cvt_wfc(const float* __restrict__ w, ushort* __restrict__ o) {
  int i = blockIdx.x * 256 + threadIdx.x;   // 8192 float4 groups
  float4 f = ((const float4*)w)[i];
  ushort4 r = { f2bfbits(f.x), f2bfbits(f.y), f2bfbits(f.z), f2bfbits(f.w) };
  *(ushort4*)(o + 4 * i) = r;
}

// ---------- 4) projection GEMM: [4096,512]bf16 @ W^T -> heads ----------
// z=0: Q (scale log2e/8, out [B,H,L,64]); z=1: K; z=2: V (out [B,H,64,L] transposed)
__global__ __launch_bounds__(256) void k_proj(
    const ushort* __restrict__ qb, const ushort* __restrict__ kb, const ushort* __restrict__ vb,
    const ushort* __restrict__ wqT, const ushort* __restrict__ wkT, const ushort* __restrict__ wvT,
    ushort* __restrict__ Qh, ushort* __restrict__ Kh, ushort* __restrict__ VhT) {
  int z = blockIdx.z;
  const ushort* A = z == 0 ? qb : (z == 1 ? kb : vb);
  const ushort* W = z == 0 ? wqT : (z == 1 ? wkT : wvT);
  ushort* Out = z == 0 ? Qh : (z == 1 ? Kh : VhT);
  // Q pre-scaled by 1/sqrt(dk) * log2(e): attention runs in exp2 domain.
  float scale = z == 0 ? 0.125f * 1.44269504088896f : 1.0f;

  int wid = threadIdx.x >> 6, l = threadIdx.x & 63;
  int lr = l & 15, lg = l >> 4;
  int row0 = blockIdx.x * 64 + wid * 16;
  int col0 = blockIdx.y * 64;
  const ushort* Arow = A + (size_t)(row0 + lr) * DM + lg * 8;

  f32x4 acc0 = {0.f, 0.f, 0.f, 0.f}, acc1 = acc0, acc2 = acc0, acc3 = acc0;
  #pragma unroll 4
  for (int kt = 0; kt < 16; ++kt) {
    bf16x8 a = *(const bf16x8*)(Arow + kt * 32);
    bf16x8 b0 = *(const bf16x8*)(W + (size_t)(col0 + 0 * 16 + lr) * DM + kt * 32 + lg * 8);
    bf16x8 b1 = *(const bf16x8*)(W + (size_t)(col0 + 1 * 16 + lr) * DM + kt * 32 + lg * 8);
    bf16x8 b2 = *(const bf16x8*)(W + (size_t)(col0 + 2 * 16 + lr) * DM + kt * 32 + lg * 8);
    bf16x8 b3 = *(const bf16x8*)(W + (size_t)(col0 + 3 * 16 + lr) * DM + kt * 32 + lg * 8);
    acc0 = __builtin_amdgcn_mfma_f32_16x16x32_bf16(a, b0, acc0, 0, 0, 0);
    acc1 = __builtin_amdgcn_mfma_f32_16x16x32_bf16(a, b1, acc1, 0, 0, 0);
    acc2 = __builtin_amdgcn_mfma_f32_16x16x32_bf16(a, b2, acc2, 0, 0, 0);
    acc3 = __builtin_amdgcn_mfma_f32_16x16x32_bf16(a, b3, acc3, 0, 0, 0);
  }
  f32x4 accs[4] = {acc0, acc1, acc2, acc3};
  #pragma unroll
  for (int ct = 0; ct < 4; ++ct) {
    int gcol = col0 + ct * 16 + lr;
    int h = gcol >> 6, d = gcol & 63;
    #pragma unroll
    for (int r = 0; r < 4; ++r) {
      int grow = row0 + lg * 4 + r;
      int bb = grow >> 10, li = grow & 1023;
      float val = accs[ct][r] * scale;
      size_t addr;
      if (z == 2) addr = ((size_t)((bb * NH + h) * DH + d)) * SL + li;
      else        addr = ((size_t)((bb * NH + h) * SL + li)) * DH + d;
      Out[addr] = f2bfbits(val);
    }
  }
}

// ---------- 5a) flash attention (no attn write): O + 1/S stats ----------
// One wave = one 16-row Q tile, barrier-free. Logits are tiny (|S|<~2), so
// no max subtraction: p = exp2(acc) unnormalized, s in one independent
// accumulator (no serial online-max chain). P bounced to PV A-fragment
// layout via per-wave DOUBLE-BUFFERED LDS (breaks cross-iter WAR chain).
__global__ __launch_bounds__(256, 2) void k_attn_flash(
    const ushort* __restrict__ Qh, const ushort* __restrict__ Kh,
    const ushort* __restrict__ VhT, float* __restrict__ O,
    float* __restrict__ invS) {
  __shared__ __align__(16) unsigned int Plds[4][2][320];  // wave × dbuf × 16q*20

  int bid = blockIdx.x;             // 0..511
  int xcd = bid & 7;
  int loc = bid >> 3;               // 0..63
  int bh  = xcd * 4 + (loc >> 4);   // 4 contiguous bh per XCD L2
  int wid = threadIdx.x >> 6, l = threadIdx.x & 63;
  int rt  = (loc & 15) * 4 + wid;   // 0..63
  int lr = l & 15, g = l >> 4;
  int q0 = rt * 16;

  const ushort* Qbase = Qh + ((size_t)(bh * SL + q0 + lr)) * DH + g * 8;
  bf16x8 bQ0 = *(const bf16x8*)(Qbase);
  bf16x8 bQ1 = *(const bf16x8*)(Qbase + 32);
  const ushort* Kbase = Kh + (size_t)bh * SL * DH + (size_t)lr * DH + g * 8;
  const ushort* Vbase = VhT + (size_t)bh * DH * SL;

  f32x4 o0 = {0.f, 0.f, 0.f, 0.f}, o1 = o0, o2 = o0, o3 = o0;
  float sacc = 0.f;

  #pragma unroll 2
  for (int kb = 0; kb < 32; ++kb) {
    unsigned int* Pw = &Plds[wid][kb & 1][0];
    #pragma unroll
    for (int c = 0; c < 2; ++c) {
      int k0 = kb * 32 + c * 16;
      const ushort* kp = Kbase + (size_t)k0 * DH;
      bf16x8 a0 = *(const bf16x8*)(kp);
      bf16x8 a1 = *(const bf16x8*)(kp + 32);
      f32x4 acc = {0.f, 0.f, 0.f, 0.f};
      acc = __builtin_amdgcn_mfma_f32_16x16x32_bf16(a0, bQ0, acc, 0, 0, 0);
      acc = __builtin_amdgcn_mfma_f32_16x16x32_bf16(a1, bQ1, acc, 0, 0, 0);
      // lane holds D[k=k0+4g+r][q=lr]
      float p0 = exp2f(acc[0]), p1 = exp2f(acc[1]);
      float p2 = exp2f(acc[2]), p3 = exp2f(acc[3]);
      sacc += (p0 + p1) + (p2 + p3);
      unsigned int pk0, pk1;
      asm("v_cvt_pk_bf16_f32 %0, %1, %2" : "=v"(pk0) : "v"(p0), "v"(p1));
      asm("v_cvt_pk_bf16_f32 %0, %1, %2" : "=v"(pk1) : "v"(p2), "v"(p3));
      uint2 w2 = { pk0, pk1 };
      *(uint2*)(Pw + lr * 20 + c * 8 + 2 * g) = w2;
    }
    // PV A-fragment: row=q=lr, k=8g..8g+7 within this 32-k block
    union { u32x4 u; bf16x8 b; } ap;
    ap.u = *(u32x4*)(Pw + lr * 20 + 4 * g);
    #pragma unroll
    for (int dt = 0; dt < 4; ++dt) {
      bf16x8 bV = *(const bf16x8*)(Vbase + (size_t)(dt * 16 + lr) * SL + kb * 32 + g * 8);
      f32x4& oo = dt == 0 ? o0 : (dt == 1 ? o1 : (dt == 2 ? o2 : o3));
      oo = __builtin_amdgcn_mfma_f32_16x16x32_bf16(ap.b, bV, oo, 0, 0, 0);
    }
  }

  // total S per q: sum the 4 k-lane-groups
  sacc += __shfl_xor(sacc, 16);
  sacc += __shfl_xor(sacc, 32);
  float inv = 1.0f / sacc;             // lane has inv for q = lr
  if (l < 16) invS[(size_t)bh * SL + q0 + l] = inv;

  float invr[4];
  #pragma unroll
  for (int r = 0; r < 4; ++r) invr[r] = __shfl(inv, 4 * g + r);

  f32x4 os[4] = { o0, o1, o2, o3 };
  #pragma unroll
  for (int dt = 0; dt < 4; ++dt)
    #pragma unroll
    for (int r = 0; r < 4; ++r)
      O[((size_t)(bh * SL + q0 + 4 * g + r)) * DH + dt * 16 + lr] = os[dt][r] * invr[r];
}

// ---------- 5b) attn materializer: recompute QK^T, stream fp32 attn ----------
// 2048 blocks (16 waves/CU). p = exp2(acc)*inv; bf16 p via XOR-swizzled 32 KB
// LDS tile; phase 2 stores fully-contiguous 1 KB/instr fp32 rows.
__global__ __launch_bounds__(256, 4) void k_attn_store(
    const ushort* __restrict__ Qh, const ushort* __restrict__ Kh,
    const float* __restrict__ invS, float* __restrict__ attn_out) {
  __shared__ __align__(16) ushort S[16 * 1024];   // 32 KB
  char* Sb = (char*)S;

  int bid = blockIdx.x;             // 0..2047
  int xcd = bid & 7;
  int loc = bid >> 3;               // 0..255
  int bh  = xcd * 4 + (loc >> 6);
  int rt  = loc & 63;
  int wid = threadIdx.x >> 6, l = threadIdx.x & 63;
  int lr = l & 15, g = l >> 4;
  int q0 = rt * 16;

  const ushort* Qbase = Qh + ((size_t)(bh * SL + q0 + lr)) * DH + g * 8;
  bf16x8 bQ0 = *(const bf16x8*)(Qbase);
  bf16x8 bQ1 = *(const bf16x8*)(Qbase + 32);
  const ushort* Kbase = Kh + (size_t)bh * SL * DH + (size_t)lr * DH + g * 8;
  float invq = invS[(size_t)bh * SL + q0 + lr];   // inv for q = lr

  // phase 1: wave wid covers k in [wid*256, wid*256+256)
  #pragma unroll 4
  for (int ct = 0; ct < 16; ++ct) {
    int k0 = wid * 256 + ct * 16;
    const ushort* kp = Kbase + (size_t)k0 * DH;
    bf16x8 a0 = *(const bf16x8*)(kp);
    bf16x8 a1 = *(const bf16x8*)(kp + 32);
    f32x4 acc = {0.f, 0.f, 0.f, 0.f};
    acc = __builtin_amdgcn_mfma_f32_16x16x32_bf16(a0, bQ0, acc, 0, 0, 0);
    acc = __builtin_amdgcn_mfma_f32_16x16x32_bf16(a1, bQ1, acc, 0, 0, 0);
    float p0 = exp2f(acc[0]) * invq, p1 = exp2f(acc[1]) * invq;
    float p2 = exp2f(acc[2]) * invq, p3 = exp2f(acc[3]) * invq;
    unsigned int pk0, pk1;
    asm("v_cvt_pk_bf16_f32 %0, %1, %2" : "=v"(pk0) : "v"(p0), "v"(p1));
    asm("v_cvt_pk_bf16_f32 %0, %1, %2" : "=v"(pk1) : "v"(p2), "v"(p3));
    uint2 w2 = { pk0, pk1 };                        // k = k0+4g .. k0+4g+3, row q=lr
    *(uint2*)(Sb + ((lr * 2048 + (k0 + 4 * g) * 2) ^ ((lr & 7) << 4))) = w2;
  }
  __syncthreads();

  // phase 2: wave wid stores rows 4wid..4wid+3, contiguous 1KB per instr
  size_t attn_base = (size_t)bh * SL * SL + (size_t)q0 * SL;
  #pragma unroll
  for (int rr = 0; rr < 4; ++rr) {
    int r = wid * 4 + rr;
    float* arow = attn_out + attn_base + (size_t)r * SL;
    #pragma unroll
    for (int i = 0; i < 4; ++i) {
      int c0 = 4 * l + 256 * i;
      uint2 u = *(uint2*)(Sb + ((r * 2048 + c0 * 2) ^ ((r & 7) << 4)));
      float4 pv;
      pv.x = bf2f((short)(u.x & 0xffff));
      pv.y = bf2f((short)(u.x >> 16));
      pv.z = bf2f((short)(u.y & 0xffff));
      pv.w = bf2f((short)(u.y >> 16));
      *(float4*)(arow + c0) = pv;
    }
  }
}

// ---------- 6) partial reduce for s: partial[b][slab][d] ----------
__global__ __launch_bounds__(256) void k_reduce(const float* __restrict__ O, float* __restrict__ partial) {
  int slab = blockIdx.x, bb = blockIdx.y;
  int d = threadIdx.x & 63, sub = threadIdx.x >> 6;
  float s = 0.f;
  for (int h = 0; h < NH; ++h) {
    const float* base = O + ((size_t)((bb * NH + h) * SL + slab * 32 + sub * 8)) * DH + d;
    #pragma unroll
    for (int li = 0; li < 8; ++li) s += base[(size_t)li * DH];
  }
  __shared__ float red[4][64];
  red[sub][d] = s;
  __syncthreads();
  if (threadIdx.x < 64) {
    float t = red[0][d] + red[1][d] + red[2][d] + red[3][d];
    partial[(bb * 32 + slab) * 64 + d] = t;
  }
}

// ---------- 7) gate: s @ w_sk, softmax over heads ----------
__global__ __launch_bounds__(256) void k_gate(const float* __restrict__ partial,
                                              const float* __restrict__ wsk, float* __restrict__ g) {
  int bb = blockIdx.x;
  int t = threadIdx.x;
  __shared__ float red[4][64];
  __shared__ float sl[64];
  __shared__ float logit[512];
  int d = t & 63, q4 = t >> 6;
  float s = 0.f;
  for (int i = 0; i < 8; ++i) s += partial[(bb * 32 + q4 * 8 + i) * 64 + d];
  red[q4][d] = s;
  __syncthreads();
  if (t < 64) sl[t] = (red[0][t] + red[1][t] + red[2][t] + red[3][t]) * (1.0f / 1024.0f);
  __syncthreads();
  #pragma unroll
  for (int jj = 0; jj < 2; ++jj) {
    int j = t + jj * 256;
    float lg = 0.f;
    #pragma unroll 8
    for (int c = 0; c < 64; ++c) lg += sl[c] * wsk[c * DM + j];
    logit[j] = lg;
  }
  __syncthreads();
  if (t < 64) {
    float m = -1e30f;
    #pragma unroll
    for (int h = 0; h < NH; ++h) m = fmaxf(m, logit[h * 64 + t]);
    float sum = 0.f, e[NH];
    #pragma unroll
    for (int h = 0; h < NH; ++h) { e[h] = __expf(logit[h * 64 + t] - m); sum += e[h]; }
    float inv = 1.0f / sum;
    #pragma unroll
    for (int h = 0; h < NH; ++h) g[bb * DM + h * 64 + t] = e[h] * inv;
  }
}

// ---------- 8) gate O -> qo, qo @ w_fc + residual, LayerNorm ----------
__global__ __launch_bounds__(256) void k_final(
    const float* __restrict__ O, const float* __restrict__ g, const ushort* __restrict__ wfc,
    const float* __restrict__ q, const float* __restrict__ gamma, const float* __restrict__ beta,
    float* __restrict__ out) {
  __shared__ __align__(16) ushort wl[32768];   // w_fc bf16, 16B-chunk swizzled [d][i8][jg]
  __shared__ __align__(16) float qo[16][64];
  __shared__ __align__(16) float gl[512];
  int lt = blockIdx.x, bb = blockIdx.y;
  int t = threadIdx.x;

  gl[t] = g[bb * DM + t];
  gl[t + 256] = g[bb * DM + 256 + t];
  {
    int jg2 = t & 15, hi = t >> 4;
    #pragma unroll
    for (int m = 0; m < 16; ++m) {
      int di = m * 16 + hi;             // 0..255
      int d = di >> 2, i8 = di & 3;
      bf16x8 w8 = *(const bf16x8*)(wfc + d * DM + jg2 * 32 + i8 * 8);
      *(bf16x8*)(wl + (size_t)(d * 64 + i8 * 16 + jg2) * 8) = w8;
    }
  }
  __syncthreads();

  int r = t >> 4, jg = t & 15;
  int l = lt * 16 + r;
  {
    float4 acc; acc.x = acc.y = acc.z = acc.w = 0.f;
    #pragma unroll
    for (int h = 0; h < NH; ++h) {
      float4 ov = *(const float4*)(O + ((size_t)((bb * NH + h) * SL + l)) * DH + jg * 4);
      float4 gv = *(const float4*)(gl + h * 64 + jg * 4);
      acc.x += ov.x * gv.x; acc.y += ov.y * gv.y; acc.z += ov.z * gv.z; acc.w += ov.w * gv.w;
    }
    *(float4*)&qo[r][jg * 4] = acc;
  }
  __syncthreads();

  float val[32];
  const float* qrow = q + ((size_t)(bb * SL + l)) * DM + jg * 32;
  #pragma unroll
  for (int i4 = 0; i4 < 8; ++i4) *(float4*)&val[i4 * 4] = *(const float4*)(qrow + i4 * 4);

  for (int d = 0; d < 64; ++d) {
    float qd = qo[r][d];
    #pragma unroll
    for (int i8 = 0; i8 < 4; ++i8) {
      bf16x8 wv8 = *(const bf16x8*)(wl + (size_t)(d * 64 + i8 * 16 + jg) * 8);
      #pragma unroll
      for (int e = 0; e < 8; ++e) val[i8 * 8 + e] += qd * bf2f(wv8[e]);
    }
  }

  float s = 0.f, ss = 0.f;
  #pragma unroll
  for (int i = 0; i < 32; ++i) { s += val[i]; ss += val[i] * val[i]; }
  #pragma unroll
  for (int m = 1; m < 16; m <<= 1) { s += __shfl_xor(s, m, 16); ss += __shfl_xor(ss, m, 16); }
  float mu = s * (1.0f / 512.0f);
  float var = ss * (1.0f / 512.0f) - mu * mu;
  float rstd = rsqrtf(var + 1e-6f);

  float* orow = out + ((size_t)(bb * SL + l)) * DM + jg * 32;
  const float* gam = gamma + jg * 32;
  const float* bet = beta + jg * 32;
  #pragma unroll
  for (int i = 0; i < 32; ++i)
    orow[i] = (val[i] - mu) * rstd * gam[i] + bet[i];
}

extern "C" void kernel_launch(void* const* d_in, const int* in_sizes, int n_in,
                              void* d_out, int out_size, void* d_ws, size_t ws_size,
                              hipStream_t stream) {
  (void)in_sizes; (void)n_in; (void)out_size; (void)ws_size;
  const float* q     = (const float*)d_in[0];
  const float* k     = (const float*)d_in[1];
  const float* v     = (const float*)d_in[2];
  const float* w_qs  = (const float*)d_in[3];
  const float* w_ks  = (const float*)d_in[4];
  const float* w_vs  = (const float*)d_in[5];
  const float* w_sk  = (const float*)d_in[6];
  const float* w_fc  = (const float*)d_in[7];
  const float* gamma = (const float*)d_in[8];
  const float* beta  = (const float*)d_in[9];

  float* out  = (float*)d_out;
  float* attn = out + (size_t)NB * SL * DM;   // 2,097,152 floats

  char* wsb = (char*)d_ws;                    // ~35.3 MB
  ushort* qb   = (ushort*)(wsb + 0);
  ushort* kb   = (ushort*)(wsb + 4194304);
  ushort* vb   = (ushort*)(wsb + 8388608);
  ushort* wqT  = (ushort*)(wsb + 12582912);
  ushort* wkT  = (ushort*)(wsb + 13107200);
  ushort* wvT  = (ushort*)(wsb + 13631488);
  ushort* wfcb = (ushort*)(wsb + 14155776);
  ushort* Qh   = (ushort*)(wsb + 14221312);
  ushort* Kh   = (ushort*)(wsb + 18415616);
  ushort* VhT  = (ushort*)(wsb + 22609920);
  float*  O    = (float*)(wsb + 26804224);
  float*  part = (float*)(wsb + 35192832);
  float*  gbuf = (float*)(wsb + 35225600);
  // invS (32K floats = 128 KB) overlays qb: qb is dead after k_proj,
  // k_attn_flash writes invS strictly after k_proj completes (same stream).
  float*  invS = (float*)(wsb + 0);

  k_cvt_act<<<dim3(2048), dim3(256), 0, stream>>>(q, k, v, qb, kb, vb);
  k_cvt_wT<<<dim3(8, 8, 3), dim3(256), 0, stream>>>(w_qs, w_ks, w_vs, wqT, wkT, wvT);
  k_cvt_wfc<<<dim3(32), dim3(256), 0, stream>>>(w_fc, wfcb);
  k_proj<<<dim3(64, 8, 3), dim3(256), 0, stream>>>(qb, kb, vb, wqT, wkT, wvT, Qh, Kh, VhT);
  k_attn_flash<<<dim3(512), dim3(256), 0, stream>>>(Qh, Kh, VhT, O, invS);
  k_attn_store<<<dim3(2048), dim3(256), 0, stream>>>(Qh, Kh, invS, attn);
  k_reduce<<<dim3(32, 4), dim3(256), 0, stream>>>(O, part);
  k_gate<<<dim3(4), dim3(256), 0, stream>>>(part, w_sk, gbuf);
  k_final<<<dim3(64, 4), dim3(256), 0, stream>>>(O, gbuf, wfcb, q, gamma, beta, out);
}

// Round 6
// 168.559 us; speedup vs baseline: 1.2008x; 1.2008x over previous
//
#include <hip/hip_runtime.h>
#include <hip/hip_bf16.h>
#include <cstdint>

#define NH 8
#define DM 512
#define DH 64
#define NB 4
#define SL 1024

typedef __attribute__((ext_vector_type(8))) short bf16x8;
typedef __attribute__((ext_vector_type(4))) float f32x4;

static __device__ __forceinline__ float bf2f(short s) {
  union { unsigned int u; float f; } c;
  c.u = ((unsigned int)(unsigned short)s) << 16;
  return c.f;
}
static __device__ __forceinline__ unsigned short f2bfbits(float f) {
  union { float f; unsigned int u; } c; c.f = f;
  unsigned int lsb = (c.u >> 16) & 1u;
  unsigned int r = c.u + 0x7fffu + lsb;   // RNE (inputs are finite/normal)
  return (unsigned short)(r >> 16);
}

// ---------- 1) fp32 -> bf16 for q,k,v (each [4096,512]) ----------
__global__ __launch_bounds__(256) void k_cvt_act(
    const float* __restrict__ q, const float* __restrict__ k, const float* __restrict__ v,
    ushort* __restrict__ qb, ushort* __restrict__ kb, ushort* __restrict__ vb) {
  int i = blockIdx.x * 256 + threadIdx.x;   // float4 group, 524288 total
  {
    float4 f = ((const float4*)q)[i];
    ushort4 r = { f2bfbits(f.x), f2bfbits(f.y), f2bfbits(f.z), f2bfbits(f.w) };
    *(ushort4*)(qb + 4 * i) = r;
  }
  {
    float4 f = ((const float4*)k)[i];
    ushort4 r = { f2bfbits(f.x), f2bfbits(f.y), f2bfbits(f.z), f2bfbits(f.w) };
    *(ushort4*)(kb + 4 * i) = r;
  }
  {
    float4 f = ((const float4*)v)[i];
    ushort4 r = { f2bfbits(f.x), f2bfbits(f.y), f2bfbits(f.z), f2bfbits(f.w) };
    *(ushort4*)(vb + 4 * i) = r;
  }
}

// ---------- 2) transpose-convert W [512,512] -> W^T bf16 ----------
__global__ __launch_bounds__(256) void k_cvt_wT(
    const float* __restrict__ w0, const float* __restrict__ w1, const float* __restrict__ w2,
    ushort* __restrict__ o0, ushort* __restrict__ o1, ushort* __restrict__ o2) {
  __shared__ ushort tile[64][65];
  const float* src = blockIdx.z == 0 ? w0 : (blockIdx.z == 1 ? w1 : w2);
  ushort* dst = blockIdx.z == 0 ? o0 : (blockIdx.z == 1 ? o1 : o2);
  int k0 = blockIdx.x * 64, n0 = blockIdx.y * 64;
  int t = threadIdx.x;
  #pragma unroll
  for (int i = 0; i < 16; ++i) {
    int lin = t + i * 256, r = lin >> 6, c = lin & 63;
    tile[r][c] = f2bfbits(src[(size_t)(k0 + r) * DM + n0 + c]);
  }
  __syncthreads();
  #pragma unroll
  for (int i = 0; i < 16; ++i) {
    int lin = t + i * 256, r = lin >> 6, c = lin & 63;
    dst[(size_t)(n0 + r) * DM + k0 + c] = tile[c][r];
  }
}

// ---------- 3) w_fc [64,512] -> bf16 ----------
__global__ __launch_bounds__(256) void k_cvt_wfc(const float* __restrict__ w, ushort* __restrict__ o) {
  int i = blockIdx.x * 256 + threadIdx.x;   // 8192 float4 groups
  float4 f = ((const float4*)w)[i];
  ushort4 r = { f2bfbits(f.x), f2bfbits(f.y), f2bfbits(f.z), f2bfbits(f.w) };
  *(ushort4*)(o + 4 * i) = r;
}

// ---------- 4) projection GEMM: [4096,512]bf16 @ W^T -> heads ----------
// z=0: Q (scale log2e/8, out [B,H,L,64]); z=1: K; z=2: V (out [B,H,64,L] transposed)
__global__ __launch_bounds__(256) void k_proj(
    const ushort* __restrict__ qb, const ushort* __restrict__ kb, const ushort* __restrict__ vb,
    const ushort* __restrict__ wqT, const ushort* __restrict__ wkT, const ushort* __restrict__ wvT,
    ushort* __restrict__ Qh, ushort* __restrict__ Kh, ushort* __restrict__ VhT) {
  int z = blockIdx.z;
  const ushort* A = z == 0 ? qb : (z == 1 ? kb : vb);
  const ushort* W = z == 0 ? wqT : (z == 1 ? wkT : wvT);
  ushort* Out = z == 0 ? Qh : (z == 1 ? Kh : VhT);
  // Q pre-scaled by 1/sqrt(dk) * log2(e): attention runs in exp2 domain.
  float scale = z == 0 ? 0.125f * 1.44269504088896f : 1.0f;

  int wid = threadIdx.x >> 6, l = threadIdx.x & 63;
  int lr = l & 15, lg = l >> 4;
  int row0 = blockIdx.x * 64 + wid * 16;
  int col0 = blockIdx.y * 64;
  const ushort* Arow = A + (size_t)(row0 + lr) * DM + lg * 8;

  f32x4 acc0 = {0.f, 0.f, 0.f, 0.f}, acc1 = acc0, acc2 = acc0, acc3 = acc0;
  #pragma unroll 4
  for (int kt = 0; kt < 16; ++kt) {
    bf16x8 a = *(const bf16x8*)(Arow + kt * 32);
    bf16x8 b0 = *(const bf16x8*)(W + (size_t)(col0 + 0 * 16 + lr) * DM + kt * 32 + lg * 8);
    bf16x8 b1 = *(const bf16x8*)(W + (size_t)(col0 + 1 * 16 + lr) * DM + kt * 32 + lg * 8);
    bf16x8 b2 = *(const bf16x8*)(W + (size_t)(col0 + 2 * 16 + lr) * DM + kt * 32 + lg * 8);
    bf16x8 b3 = *(const bf16x8*)(W + (size_t)(col0 + 3 * 16 + lr) * DM + kt * 32 + lg * 8);
    acc0 = __builtin_amdgcn_mfma_f32_16x16x32_bf16(a, b0, acc0, 0, 0, 0);
    acc1 = __builtin_amdgcn_mfma_f32_16x16x32_bf16(a, b1, acc1, 0, 0, 0);
    acc2 = __builtin_amdgcn_mfma_f32_16x16x32_bf16(a, b2, acc2, 0, 0, 0);
    acc3 = __builtin_amdgcn_mfma_f32_16x16x32_bf16(a, b3, acc3, 0, 0, 0);
  }
  f32x4 accs[4] = {acc0, acc1, acc2, acc3};
  #pragma unroll
  for (int ct = 0; ct < 4; ++ct) {
    int gcol = col0 + ct * 16 + lr;
    int h = gcol >> 6, d = gcol & 63;
    #pragma unroll
    for (int r = 0; r < 4; ++r) {
      int grow = row0 + lg * 4 + r;
      int bb = grow >> 10, li = grow & 1023;
      float val = accs[ct][r] * scale;
      size_t addr;
      if (z == 2) addr = ((size_t)((bb * NH + h) * DH + d)) * SL + li;
      else        addr = ((size_t)((bb * NH + h) * SL + li)) * DH + d;
      Out[addr] = f2bfbits(val);
    }
  }
}

// ---------- 5) fused attention: 2 phases, 1 barrier ----------
// Swapped QK^T (mfma(K,Q): lane holds p for q=lane&15). No-max exp2 softmax:
// phase 1 writes UNNORMALIZED bf16 p to swizzled LDS and accumulates the row
// sum in a single register per lane. Phase 2 normalizes at read time: attn
// rows stream as contiguous float4; PV runs on unnormalized P, O *= inv at
// the end (PV is linear in P).
__global__ __launch_bounds__(256, 4) void k_attn(
    const ushort* __restrict__ Qh, const ushort* __restrict__ Kh, const ushort* __restrict__ VhT,
    float* __restrict__ attn_out, float* __restrict__ O) {
  __shared__ __align__(16) ushort S[16 * 1024];   // 32 KB, byte ^= (q&7)<<4
  __shared__ float spart[4][16];                  // per-wave partial row sums
  char* Sb = (char*)S;

  int bid = blockIdx.x;             // 0..2047
  int xcd = bid & 7;
  int loc = bid >> 3;               // 0..255
  int bh  = xcd * 4 + (loc >> 6);   // 4 contiguous bh per XCD L2
  int rt  = loc & 63;
  int wid = threadIdx.x >> 6, l = threadIdx.x & 63;
  int lr = l & 15, g = l >> 4;
  int q0 = rt * 16;

  // Q fragment (B-operand of swapped QK^T): col=lane&15 -> q row
  const ushort* Qbase = Qh + ((size_t)(bh * SL + q0 + lr)) * DH + g * 8;
  bf16x8 bQ0 = *(const bf16x8*)(Qbase);
  bf16x8 bQ1 = *(const bf16x8*)(Qbase + 32);
  const ushort* Kbase = Kh + (size_t)bh * SL * DH + (size_t)lr * DH + g * 8;

  // ---- phase 1: QK^T, p=exp2(acc) unnormalized -> LDS; row-sum in reg ----
  // wave wid covers k in [wid*256, wid*256+256); lane accumulates sum for q=lr
  float sacc = 0.f;
  #pragma unroll 4
  for (int ct = 0; ct < 16; ++ct) {
    int k0 = wid * 256 + ct * 16;
    const ushort* kp = Kbase + (size_t)k0 * DH;
    bf16x8 a0 = *(const bf16x8*)(kp);
    bf16x8 a1 = *(const bf16x8*)(kp + 32);
    f32x4 acc = {0.f, 0.f, 0.f, 0.f};
    acc = __builtin_amdgcn_mfma_f32_16x16x32_bf16(a0, bQ0, acc, 0, 0, 0);
    acc = __builtin_amdgcn_mfma_f32_16x16x32_bf16(a1, bQ1, acc, 0, 0, 0);
    // lane holds D[k=k0+4g+r][q=lr]
    float p0 = exp2f(acc[0]), p1 = exp2f(acc[1]);
    float p2 = exp2f(acc[2]), p3 = exp2f(acc[3]);
    sacc += (p0 + p1) + (p2 + p3);
    unsigned int pk0, pk1;
    asm("v_cvt_pk_bf16_f32 %0, %1, %2" : "=v"(pk0) : "v"(p0), "v"(p1));
    asm("v_cvt_pk_bf16_f32 %0, %1, %2" : "=v"(pk1) : "v"(p2), "v"(p3));
    uint2 w2 = { pk0, pk1 };                       // k = k0+4g..k0+4g+3, q = lr
    *(uint2*)(Sb + (((lr << 11) + ((k0 + 4 * g) << 1)) ^ ((lr & 7) << 4))) = w2;
  }
  // sum the 4 k-lane-groups sharing q=lr
  sacc += __shfl_xor(sacc, 16);
  sacc += __shfl_xor(sacc, 32);
  if (l < 16) spart[wid][l] = sacc;
  __syncthreads();

  // ---- phase 2a: attn store, rows 4wid..4wid+3, contiguous 1KB/instr ----
  size_t attn_base = (size_t)bh * SL * SL + (size_t)q0 * SL;
  #pragma unroll
  for (int rr = 0; rr < 4; ++rr) {
    int r = wid * 4 + rr;
    float inv = 1.0f / (spart[0][r] + spart[1][r] + spart[2][r] + spart[3][r]);
    float* arow = attn_out + attn_base + (size_t)r * SL;
    #pragma unroll
    for (int i = 0; i < 4; ++i) {
      int c0 = 4 * l + 256 * i;
      uint2 u = *(uint2*)(Sb + (((r << 11) + (c0 << 1)) ^ ((r & 7) << 4)));
      float4 pv;
      pv.x = bf2f((short)(u.x & 0xffff)) * inv;
      pv.y = bf2f((short)(u.x >> 16)) * inv;
      pv.z = bf2f((short)(u.y & 0xffff)) * inv;
      pv.w = bf2f((short)(u.y >> 16)) * inv;
      *(float4*)(arow + c0) = pv;
    }
  }

  // ---- phase 2b: PV on unnormalized P; wave wid -> O cols [wid*16, +16) ----
  const ushort* Vbase = VhT + (size_t)bh * DH * SL + (size_t)(wid * 16 + lr) * SL + g * 8;
  f32x4 acc = {0.f, 0.f, 0.f, 0.f};
  #pragma unroll 8
  for (int kt = 0; kt < 32; ++kt) {
    bf16x8 aP = *(const bf16x8*)(Sb + (((lr << 11) + ((kt * 32 + g * 8) << 1)) ^ ((lr & 7) << 4)));
    bf16x8 bV = *(const bf16x8*)(Vbase + kt * 32);
    acc = __builtin_amdgcn_mfma_f32_16x16x32_bf16(aP, bV, acc, 0, 0, 0);
  }
  // D[q=4g+r][d=wid*16+lr]; normalize by inv[q]
  #pragma unroll
  for (int r = 0; r < 4; ++r) {
    int qr = 4 * g + r;
    float inv = 1.0f / (spart[0][qr] + spart[1][qr] + spart[2][qr] + spart[3][qr]);
    O[((size_t)(bh * SL + q0 + qr)) * DH + wid * 16 + lr] = acc[r] * inv;
  }
}

// ---------- 6) partial reduce for s: partial[b][slab][d] ----------
__global__ __launch_bounds__(256) void k_reduce(const float* __restrict__ O, float* __restrict__ partial) {
  int slab = blockIdx.x, bb = blockIdx.y;
  int d = threadIdx.x & 63, sub = threadIdx.x >> 6;
  float s = 0.f;
  for (int h = 0; h < NH; ++h) {
    const float* base = O + ((size_t)((bb * NH + h) * SL + slab * 32 + sub * 8)) * DH + d;
    #pragma unroll
    for (int li = 0; li < 8; ++li) s += base[(size_t)li * DH];
  }
  __shared__ float red[4][64];
  red[sub][d] = s;
  __syncthreads();
  if (threadIdx.x < 64) {
    float t = red[0][d] + red[1][d] + red[2][d] + red[3][d];
    partial[(bb * 32 + slab) * 64 + d] = t;
  }
}

// ---------- 7) gate: s @ w_sk, softmax over heads ----------
__global__ __launch_bounds__(256) void k_gate(const float* __restrict__ partial,
                                              const float* __restrict__ wsk, float* __restrict__ g) {
  int bb = blockIdx.x;
  int t = threadIdx.x;
  __shared__ float red[4][64];
  __shared__ float sl[64];
  __shared__ float logit[512];
  int d = t & 63, q4 = t >> 6;
  float s = 0.f;
  for (int i = 0; i < 8; ++i) s += partial[(bb * 32 + q4 * 8 + i) * 64 + d];
  red[q4][d] = s;
  __syncthreads();
  if (t < 64) sl[t] = (red[0][t] + red[1][t] + red[2][t] + red[3][t]) * (1.0f / 1024.0f);
  __syncthreads();
  #pragma unroll
  for (int jj = 0; jj < 2; ++jj) {
    int j = t + jj * 256;
    float lg = 0.f;
    #pragma unroll 8
    for (int c = 0; c < 64; ++c) lg += sl[c] * wsk[c * DM + j];
    logit[j] = lg;
  }
  __syncthreads();
  if (t < 64) {
    float m = -1e30f;
    #pragma unroll
    for (int h = 0; h < NH; ++h) m = fmaxf(m, logit[h * 64 + t]);
    float sum = 0.f, e[NH];
    #pragma unroll
    for (int h = 0; h < NH; ++h) { e[h] = __expf(logit[h * 64 + t] - m); sum += e[h]; }
    float inv = 1.0f / sum;
    #pragma unroll
    for (int h = 0; h < NH; ++h) g[bb * DM + h * 64 + t] = e[h] * inv;
  }
}

// ---------- 8) gate O -> qo, qo @ w_fc + residual, LayerNorm ----------
__global__ __launch_bounds__(256) void k_final(
    const float* __restrict__ O, const float* __restrict__ g, const ushort* __restrict__ wfc,
    const float* __restrict__ q, const float* __restrict__ gamma, const float* __restrict__ beta,
    float* __restrict__ out) {
  __shared__ __align__(16) ushort wl[32768];   // w_fc bf16, 16B-chunk swizzled [d][i8][jg]
  __shared__ __align__(16) float qo[16][64];
  __shared__ __align__(16) float gl[512];
  int lt = blockIdx.x, bb = blockIdx.y;
  int t = threadIdx.x;

  gl[t] = g[bb * DM + t];
  gl[t + 256] = g[bb * DM + 256 + t];
  {
    int jg2 = t & 15, hi = t >> 4;
    #pragma unroll
    for (int m = 0; m < 16; ++m) {
      int di = m * 16 + hi;             // 0..255
      int d = di >> 2, i8 = di & 3;
      bf16x8 w8 = *(const bf16x8*)(wfc + d * DM + jg2 * 32 + i8 * 8);
      *(bf16x8*)(wl + (size_t)(d * 64 + i8 * 16 + jg2) * 8) = w8;
    }
  }
  __syncthreads();

  int r = t >> 4, jg = t & 15;
  int l = lt * 16 + r;
  {
    float4 acc; acc.x = acc.y = acc.z = acc.w = 0.f;
    #pragma unroll
    for (int h = 0; h < NH; ++h) {
      float4 ov = *(const float4*)(O + ((size_t)((bb * NH + h) * SL + l)) * DH + jg * 4);
      float4 gv = *(const float4*)(gl + h * 64 + jg * 4);
      acc.x += ov.x * gv.x; acc.y += ov.y * gv.y; acc.z += ov.z * gv.z; acc.w += ov.w * gv.w;
    }
    *(float4*)&qo[r][jg * 4] = acc;
  }
  __syncthreads();

  float val[32];
  const float* qrow = q + ((size_t)(bb * SL + l)) * DM + jg * 32;
  #pragma unroll
  for (int i4 = 0; i4 < 8; ++i4) *(float4*)&val[i4 * 4] = *(const float4*)(qrow + i4 * 4);

  for (int d = 0; d < 64; ++d) {
    float qd = qo[r][d];
    #pragma unroll
    for (int i8 = 0; i8 < 4; ++i8) {
      bf16x8 wv8 = *(const bf16x8*)(wl + (size_t)(d * 64 + i8 * 16 + jg) * 8);
      #pragma unroll
      for (int e = 0; e < 8; ++e) val[i8 * 8 + e] += qd * bf2f(wv8[e]);
    }
  }

  float s = 0.f, ss = 0.f;
  #pragma unroll
  for (int i = 0; i < 32; ++i) { s += val[i]; ss += val[i] * val[i]; }
  #pragma unroll
  for (int m = 1; m < 16; m <<= 1) { s += __shfl_xor(s, m, 16); ss += __shfl_xor(ss, m, 16); }
  float mu = s * (1.0f / 512.0f);
  float var = ss * (1.0f / 512.0f) - mu * mu;
  float rstd = rsqrtf(var + 1e-6f);

  float* orow = out + ((size_t)(bb * SL + l)) * DM + jg * 32;
  const float* gam = gamma + jg * 32;
  const float* bet = beta + jg * 32;
  #pragma unroll
  for (int i = 0; i < 32; ++i)
    orow[i] = (val[i] - mu) * rstd * gam[i] + bet[i];
}

extern "C" void kernel_launch(void* const* d_in, const int* in_sizes, int n_in,
                              void* d_out, int out_size, void* d_ws, size_t ws_size,
                              hipStream_t stream) {
  (void)in_sizes; (void)n_in; (void)out_size; (void)ws_size;
  const float* q     = (const float*)d_in[0];
  const float* k     = (const float*)d_in[1];
  const float* v     = (const float*)d_in[2];
  const float* w_qs  = (const float*)d_in[3];
  const float* w_ks  = (const float*)d_in[4];
  const float* w_vs  = (const float*)d_in[5];
  const float* w_sk  = (const float*)d_in[6];
  const float* w_fc  = (const float*)d_in[7];
  const float* gamma = (const float*)d_in[8];
  const float* beta  = (const float*)d_in[9];

  float* out  = (float*)d_out;
  float* attn = out + (size_t)NB * SL * DM;   // 2,097,152 floats

  char* wsb = (char*)d_ws;                    // ~35.3 MB
  ushort* qb   = (ushort*)(wsb + 0);
  ushort* kb   = (ushort*)(wsb + 4194304);
  ushort* vb   = (ushort*)(wsb + 8388608);
  ushort* wqT  = (ushort*)(wsb + 12582912);
  ushort* wkT  = (ushort*)(wsb + 13107200);
  ushort* wvT  = (ushort*)(wsb + 13631488);
  ushort* wfcb = (ushort*)(wsb + 14155776);
  ushort* Qh   = (ushort*)(wsb + 14221312);
  ushort* Kh   = (ushort*)(wsb + 18415616);
  ushort* VhT  = (ushort*)(wsb + 22609920);
  float*  O    = (float*)(wsb + 26804224);
  float*  part = (float*)(wsb + 35192832);
  float*  gbuf = (float*)(wsb + 35225600);

  k_cvt_act<<<dim3(2048), dim3(256), 0, stream>>>(q, k, v, qb, kb, vb);
  k_cvt_wT<<<dim3(8, 8, 3), dim3(256), 0, stream>>>(w_qs, w_ks, w_vs, wqT, wkT, wvT);
  k_cvt_wfc<<<dim3(32), dim3(256), 0, stream>>>(w_fc, wfcb);
  k_proj<<<dim3(64, 8, 3), dim3(256), 0, stream>>>(qb, kb, vb, wqT, wkT, wvT, Qh, Kh, VhT);
  k_attn<<<dim3(2048), dim3(256), 0, stream>>>(Qh, Kh, VhT, attn, O);
  k_reduce<<<dim3(32, 4), dim3(256), 0, stream>>>(O, part);
  k_gate<<<dim3(4), dim3(256), 0, stream>>>(part, w_sk, gbuf);
  k_final<<<dim3(64, 4), dim3(256), 0, stream>>>(O, gbuf, wfcb, q, gamma, beta, out);
}

// Round 7
// 165.077 us; speedup vs baseline: 1.2262x; 1.0211x over previous
//
#include <hip/hip_runtime.h>
#include <hip/hip_bf16.h>
#include <cstdint>

#define NH 8
#define DM 512
#define DH 64
#define NB 4
#define SL 1024

typedef __attribute__((ext_vector_type(8))) short bf16x8;
typedef __attribute__((ext_vector_type(4))) float f32x4;

static __device__ __forceinline__ float bf2f(short s) {
  union { unsigned int u; float f; } c;
  c.u = ((unsigned int)(unsigned short)s) << 16;
  return c.f;
}
static __device__ __forceinline__ unsigned short f2bfbits(float f) {
  union { float f; unsigned int u; } c; c.f = f;
  unsigned int lsb = (c.u >> 16) & 1u;
  unsigned int r = c.u + 0x7fffu + lsb;   // RNE (inputs are finite/normal)
  return (unsigned short)(r >> 16);
}

// ---------- 1) merged converts: qkv fp32->bf16, W^T transpose, w_fc ----------
// blocks 0..2047: qkv; 2048..2239: W transpose (3x8x8); 2240..2271: w_fc
__global__ __launch_bounds__(256) void k_cvt_all(
    const float* __restrict__ q, const float* __restrict__ k, const float* __restrict__ v,
    ushort* __restrict__ qb, ushort* __restrict__ kb, ushort* __restrict__ vb,
    const float* __restrict__ w0, const float* __restrict__ w1, const float* __restrict__ w2,
    ushort* __restrict__ o0, ushort* __restrict__ o1, ushort* __restrict__ o2,
    const float* __restrict__ wfc, ushort* __restrict__ wfcb) {
  __shared__ ushort tile[64][65];
  int b = blockIdx.x, t = threadIdx.x;
  if (b < 2048) {
    int i = b * 256 + t;
    {
      float4 f = ((const float4*)q)[i];
      ushort4 r = { f2bfbits(f.x), f2bfbits(f.y), f2bfbits(f.z), f2bfbits(f.w) };
      *(ushort4*)(qb + 4 * i) = r;
    }
    {
      float4 f = ((const float4*)k)[i];
      ushort4 r = { f2bfbits(f.x), f2bfbits(f.y), f2bfbits(f.z), f2bfbits(f.w) };
      *(ushort4*)(kb + 4 * i) = r;
    }
    {
      float4 f = ((const float4*)v)[i];
      ushort4 r = { f2bfbits(f.x), f2bfbits(f.y), f2bfbits(f.z), f2bfbits(f.w) };
      *(ushort4*)(vb + 4 * i) = r;
    }
  } else if (b < 2240) {
    int idx = b - 2048;           // 0..191
    int z = idx >> 6, rem = idx & 63;
    int k0 = (rem & 7) * 64, n0 = (rem >> 3) * 64;
    const float* src = z == 0 ? w0 : (z == 1 ? w1 : w2);
    ushort* dst = z == 0 ? o0 : (z == 1 ? o1 : o2);
    #pragma unroll
    for (int i = 0; i < 16; ++i) {
      int lin = t + i * 256, r = lin >> 6, c = lin & 63;
      tile[r][c] = f2bfbits(src[(size_t)(k0 + r) * DM + n0 + c]);
    }
    __syncthreads();
    #pragma unroll
    for (int i = 0; i < 16; ++i) {
      int lin = t + i * 256, r = lin >> 6, c = lin & 63;
      dst[(size_t)(n0 + r) * DM + k0 + c] = tile[c][r];
    }
  } else {
    int i = (b - 2240) * 256 + t;   // 8192 float4 groups
    float4 f = ((const float4*)wfc)[i];
    ushort4 r = { f2bfbits(f.x), f2bfbits(f.y), f2bfbits(f.z), f2bfbits(f.w) };
    *(ushort4*)(wfcb + 4 * i) = r;
  }
}

// ---------- 4) projection GEMM: [4096,512]bf16 @ W^T -> heads ----------
// z=0: Q (scale log2e/8, out [B,H,L,64]); z=1: K; z=2: V (out [B,H,64,L] transposed)
__global__ __launch_bounds__(256) void k_proj(
    const ushort* __restrict__ qb, const ushort* __restrict__ kb, const ushort* __restrict__ vb,
    const ushort* __restrict__ wqT, const ushort* __restrict__ wkT, const ushort* __restrict__ wvT,
    ushort* __restrict__ Qh, ushort* __restrict__ Kh, ushort* __restrict__ VhT) {
  int z = blockIdx.z;
  const ushort* A = z == 0 ? qb : (z == 1 ? kb : vb);
  const ushort* W = z == 0 ? wqT : (z == 1 ? wkT : wvT);
  ushort* Out = z == 0 ? Qh : (z == 1 ? Kh : VhT);
  // Q pre-scaled by 1/sqrt(dk) * log2(e): attention runs in exp2 domain.
  float scale = z == 0 ? 0.125f * 1.44269504088896f : 1.0f;

  int wid = threadIdx.x >> 6, l = threadIdx.x & 63;
  int lr = l & 15, lg = l >> 4;
  int row0 = blockIdx.x * 64 + wid * 16;
  int col0 = blockIdx.y * 64;
  const ushort* Arow = A + (size_t)(row0 + lr) * DM + lg * 8;

  f32x4 acc0 = {0.f, 0.f, 0.f, 0.f}, acc1 = acc0, acc2 = acc0, acc3 = acc0;
  #pragma unroll 4
  for (int kt = 0; kt < 16; ++kt) {
    bf16x8 a = *(const bf16x8*)(Arow + kt * 32);
    bf16x8 b0 = *(const bf16x8*)(W + (size_t)(col0 + 0 * 16 + lr) * DM + kt * 32 + lg * 8);
    bf16x8 b1 = *(const bf16x8*)(W + (size_t)(col0 + 1 * 16 + lr) * DM + kt * 32 + lg * 8);
    bf16x8 b2 = *(const bf16x8*)(W + (size_t)(col0 + 2 * 16 + lr) * DM + kt * 32 + lg * 8);
    bf16x8 b3 = *(const bf16x8*)(W + (size_t)(col0 + 3 * 16 + lr) * DM + kt * 32 + lg * 8);
    acc0 = __builtin_amdgcn_mfma_f32_16x16x32_bf16(a, b0, acc0, 0, 0, 0);
    acc1 = __builtin_amdgcn_mfma_f32_16x16x32_bf16(a, b1, acc1, 0, 0, 0);
    acc2 = __builtin_amdgcn_mfma_f32_16x16x32_bf16(a, b2, acc2, 0, 0, 0);
    acc3 = __builtin_amdgcn_mfma_f32_16x16x32_bf16(a, b3, acc3, 0, 0, 0);
  }
  f32x4 accs[4] = {acc0, acc1, acc2, acc3};
  #pragma unroll
  for (int ct = 0; ct < 4; ++ct) {
    int gcol = col0 + ct * 16 + lr;
    int h = gcol >> 6, d = gcol & 63;
    #pragma unroll
    for (int r = 0; r < 4; ++r) {
      int grow = row0 + lg * 4 + r;
      int bb = grow >> 10, li = grow & 1023;
      float val = accs[ct][r] * scale;
      size_t addr;
      if (z == 2) addr = ((size_t)((bb * NH + h) * DH + d)) * SL + li;
      else        addr = ((size_t)((bb * NH + h) * SL + li)) * DH + d;
      Out[addr] = f2bfbits(val);
    }
  }
}

// ---------- 5) fused attention: 2 phases, 1 barrier ----------
// Swapped QK^T (mfma(K,Q): lane holds p for q=lane&15). No-max exp2 softmax:
// phase 1 writes UNNORMALIZED bf16 p to swizzled LDS, row sums in regs.
// Phase 2 ORDERING RULE (vmcnt completes in-order): all V loads are issued
// BEFORE any attn store, in two halves, so PV MFMA never waits on the 16 KB
// per-wave attn write drain. Stores interleave between MFMA half-phases.
__global__ __launch_bounds__(256, 4) void k_attn(
    const ushort* __restrict__ Qh, const ushort* __restrict__ Kh, const ushort* __restrict__ VhT,
    float* __restrict__ attn_out, float* __restrict__ O) {
  __shared__ __align__(16) ushort S[16 * 1024];   // 32 KB, byte ^= (q&7)<<4
  __shared__ float spart[4][16];                  // per-wave partial row sums
  char* Sb = (char*)S;

  int bid = blockIdx.x;             // 0..2047
  int xcd = bid & 7;
  int loc = bid >> 3;               // 0..255
  int bh  = xcd * 4 + (loc >> 6);   // 4 contiguous bh per XCD L2
  int rt  = loc & 63;
  int wid = threadIdx.x >> 6, l = threadIdx.x & 63;
  int lr = l & 15, g = l >> 4;
  int q0 = rt * 16;

  // Q fragment (B-operand of swapped QK^T): col=lane&15 -> q row
  const ushort* Qbase = Qh + ((size_t)(bh * SL + q0 + lr)) * DH + g * 8;
  bf16x8 bQ0 = *(const bf16x8*)(Qbase);
  bf16x8 bQ1 = *(const bf16x8*)(Qbase + 32);
  const ushort* Kbase = Kh + (size_t)bh * SL * DH + (size_t)lr * DH + g * 8;

  // ---- phase 1: QK^T, p=exp2(acc) unnormalized -> LDS; row-sum in reg ----
  float sacc = 0.f;
  #pragma unroll 4
  for (int ct = 0; ct < 16; ++ct) {
    int k0 = wid * 256 + ct * 16;
    const ushort* kp = Kbase + (size_t)k0 * DH;
    bf16x8 a0 = *(const bf16x8*)(kp);
    bf16x8 a1 = *(const bf16x8*)(kp + 32);
    f32x4 acc = {0.f, 0.f, 0.f, 0.f};
    acc = __builtin_amdgcn_mfma_f32_16x16x32_bf16(a0, bQ0, acc, 0, 0, 0);
    acc = __builtin_amdgcn_mfma_f32_16x16x32_bf16(a1, bQ1, acc, 0, 0, 0);
    // lane holds D[k=k0+4g+r][q=lr]
    float p0 = exp2f(acc[0]), p1 = exp2f(acc[1]);
    float p2 = exp2f(acc[2]), p3 = exp2f(acc[3]);
    sacc += (p0 + p1) + (p2 + p3);
    unsigned int pk0, pk1;
    asm("v_cvt_pk_bf16_f32 %0, %1, %2" : "=v"(pk0) : "v"(p0), "v"(p1));
    asm("v_cvt_pk_bf16_f32 %0, %1, %2" : "=v"(pk1) : "v"(p2), "v"(p3));
    uint2 w2 = { pk0, pk1 };                       // k = k0+4g..k0+4g+3, q = lr
    *(uint2*)(Sb + (((lr << 11) + ((k0 + 4 * g) << 1)) ^ ((lr & 7) << 4))) = w2;
  }
  // sum the 4 k-lane-groups sharing q=lr
  sacc += __shfl_xor(sacc, 16);
  sacc += __shfl_xor(sacc, 32);
  if (l < 16) spart[wid][l] = sacc;
  __syncthreads();

  // per-row inverses
  float invs[4];   // rows wid*4+rr (attn store rows)
  #pragma unroll
  for (int rr = 0; rr < 4; ++rr) {
    int r = wid * 4 + rr;
    invs[rr] = 1.0f / (spart[0][r] + spart[1][r] + spart[2][r] + spart[3][r]);
  }
  float invo[4];   // rows 4g+r (O rows)
  #pragma unroll
  for (int r = 0; r < 4; ++r) {
    int qr = 4 * g + r;
    invo[r] = 1.0f / (spart[0][qr] + spart[1][qr] + spart[2][qr] + spart[3][qr]);
  }

  const ushort* Vbase = VhT + (size_t)bh * DH * SL + (size_t)(wid * 16 + lr) * SL + g * 8;
  size_t attn_base = (size_t)bh * SL * SL + (size_t)q0 * SL;
  f32x4 acc = {0.f, 0.f, 0.f, 0.f};
  bf16x8 va[16];

  // ---- half A: V loads 0..15 issued first, then MFMA ----
  #pragma unroll
  for (int kt = 0; kt < 16; ++kt) va[kt] = *(const bf16x8*)(Vbase + kt * 32);
  #pragma unroll
  for (int kt = 0; kt < 16; ++kt) {
    bf16x8 aP = *(const bf16x8*)(Sb + (((lr << 11) + ((kt * 32 + g * 8) << 1)) ^ ((lr & 7) << 4)));
    acc = __builtin_amdgcn_mfma_f32_16x16x32_bf16(aP, va[kt], acc, 0, 0, 0);
  }
  // ---- half B: V loads 16..31 (BEFORE any store) ----
  #pragma unroll
  for (int kt = 0; kt < 16; ++kt) va[kt] = *(const bf16x8*)(Vbase + (16 + kt) * 32);
  // ---- attn stores, first half (rows wid*4+rr, cols 4l + 256*{0,1}) ----
  #pragma unroll
  for (int j = 0; j < 8; ++j) {
    int rr = j >> 1, i = j & 1;
    int r = wid * 4 + rr;
    int c0 = 4 * l + 256 * i;
    uint2 u = *(uint2*)(Sb + (((r << 11) + (c0 << 1)) ^ ((r & 7) << 4)));
    float4 pv;
    pv.x = bf2f((short)(u.x & 0xffff)) * invs[rr];
    pv.y = bf2f((short)(u.x >> 16)) * invs[rr];
    pv.z = bf2f((short)(u.y & 0xffff)) * invs[rr];
    pv.w = bf2f((short)(u.y >> 16)) * invs[rr];
    *(float4*)(attn_out + attn_base + (size_t)r * SL + c0) = pv;
  }
  // ---- MFMA half B (V already in regs; waits only on older loads) ----
  #pragma unroll
  for (int kt = 0; kt < 16; ++kt) {
    bf16x8 aP = *(const bf16x8*)(Sb + (((lr << 11) + (((16 + kt) * 32 + g * 8) << 1)) ^ ((lr & 7) << 4)));
    acc = __builtin_amdgcn_mfma_f32_16x16x32_bf16(aP, va[kt], acc, 0, 0, 0);
  }
  // ---- attn stores, second half ----
  #pragma unroll
  for (int j = 0; j < 8; ++j) {
    int rr = j >> 1, i = 2 + (j & 1);
    int r = wid * 4 + rr;
    int c0 = 4 * l + 256 * i;
    uint2 u = *(uint2*)(Sb + (((r << 11) + (c0 << 1)) ^ ((r & 7) << 4)));
    float4 pv;
    pv.x = bf2f((short)(u.x & 0xffff)) * invs[rr];
    pv.y = bf2f((short)(u.x >> 16)) * invs[rr];
    pv.z = bf2f((short)(u.y & 0xffff)) * invs[rr];
    pv.w = bf2f((short)(u.y >> 16)) * invs[rr];
    *(float4*)(attn_out + attn_base + (size_t)r * SL + c0) = pv;
  }
  // ---- O store: D[q=4g+r][d=wid*16+lr], normalized ----
  #pragma unroll
  for (int r = 0; r < 4; ++r)
    O[((size_t)(bh * SL + q0 + 4 * g + r)) * DH + wid * 16 + lr] = acc[r] * invo[r];
}

// ---------- 6) partial reduce for s: partial[b][slab][d] ----------
__global__ __launch_bounds__(256) void k_reduce(const float* __restrict__ O, float* __restrict__ partial) {
  int slab = blockIdx.x, bb = blockIdx.y;
  int d = threadIdx.x & 63, sub = threadIdx.x >> 6;
  float s = 0.f;
  for (int h = 0; h < NH; ++h) {
    const float* base = O + ((size_t)((bb * NH + h) * SL + slab * 32 + sub * 8)) * DH + d;
    #pragma unroll
    for (int li = 0; li < 8; ++li) s += base[(size_t)li * DH];
  }
  __shared__ float red[4][64];
  red[sub][d] = s;
  __syncthreads();
  if (threadIdx.x < 64) {
    float t = red[0][d] + red[1][d] + red[2][d] + red[3][d];
    partial[(bb * 32 + slab) * 64 + d] = t;
  }
}

// ---------- 7) gate: s @ w_sk, softmax over heads ----------
__global__ __launch_bounds__(256) void k_gate(const float* __restrict__ partial,
                                              const float* __restrict__ wsk, float* __restrict__ g) {
  int bb = blockIdx.x;
  int t = threadIdx.x;
  __shared__ float red[4][64];
  __shared__ float sl[64];
  __shared__ float logit[512];
  int d = t & 63, q4 = t >> 6;
  float s = 0.f;
  for (int i = 0; i < 8; ++i) s += partial[(bb * 32 + q4 * 8 + i) * 64 + d];
  red[q4][d] = s;
  __syncthreads();
  if (t < 64) sl[t] = (red[0][t] + red[1][t] + red[2][t] + red[3][t]) * (1.0f / 1024.0f);
  __syncthreads();
  #pragma unroll
  for (int jj = 0; jj < 2; ++jj) {
    int j = t + jj * 256;
    float lg = 0.f;
    #pragma unroll 8
    for (int c = 0; c < 64; ++c) lg += sl[c] * wsk[c * DM + j];
    logit[j] = lg;
  }
  __syncthreads();
  if (t < 64) {
    float m = -1e30f;
    #pragma unroll
    for (int h = 0; h < NH; ++h) m = fmaxf(m, logit[h * 64 + t]);
    float sum = 0.f, e[NH];
    #pragma unroll
    for (int h = 0; h < NH; ++h) { e[h] = __expf(logit[h * 64 + t] - m); sum += e[h]; }
    float inv = 1.0f / sum;
    #pragma unroll
    for (int h = 0; h < NH; ++h) g[bb * DM + h * 64 + t] = e[h] * inv;
  }
}

// ---------- 8) gate O -> qo, qo @ w_fc + residual, LayerNorm ----------
__global__ __launch_bounds__(256) void k_final(
    const float* __restrict__ O, const float* __restrict__ g, const ushort* __restrict__ wfc,
    const float* __restrict__ q, const float* __restrict__ gamma, const float* __restrict__ beta,
    float* __restrict__ out) {
  __shared__ __align__(16) ushort wl[32768];   // w_fc bf16, 16B-chunk swizzled [d][i8][jg]
  __shared__ __align__(16) float qo[16][64];
  __shared__ __align__(16) float gl[512];
  int lt = blockIdx.x, bb = blockIdx.y;
  int t = threadIdx.x;

  gl[t] = g[bb * DM + t];
  gl[t + 256] = g[bb * DM + 256 + t];
  {
    int jg2 = t & 15, hi = t >> 4;
    #pragma unroll
    for (int m = 0; m < 16; ++m) {
      int di = m * 16 + hi;             // 0..255
      int d = di >> 2, i8 = di & 3;
      bf16x8 w8 = *(const bf16x8*)(wfc + d * DM + jg2 * 32 + i8 * 8);
      *(bf16x8*)(wl + (size_t)(d * 64 + i8 * 16 + jg2) * 8) = w8;
    }
  }
  __syncthreads();

  int r = t >> 4, jg = t & 15;
  int l = lt * 16 + r;
  {
    float4 acc; acc.x = acc.y = acc.z = acc.w = 0.f;
    #pragma unroll
    for (int h = 0; h < NH; ++h) {
      float4 ov = *(const float4*)(O + ((size_t)((bb * NH + h) * SL + l)) * DH + jg * 4);
      float4 gv = *(const float4*)(gl + h * 64 + jg * 4);
      acc.x += ov.x * gv.x; acc.y += ov.y * gv.y; acc.z += ov.z * gv.z; acc.w += ov.w * gv.w;
    }
    *(float4*)&qo[r][jg * 4] = acc;
  }
  __syncthreads();

  float val[32];
  const float* qrow = q + ((size_t)(bb * SL + l)) * DM + jg * 32;
  #pragma unroll
  for (int i4 = 0; i4 < 8; ++i4) *(float4*)&val[i4 * 4] = *(const float4*)(qrow + i4 * 4);

  for (int d = 0; d < 64; ++d) {
    float qd = qo[r][d];
    #pragma unroll
    for (int i8 = 0; i8 < 4; ++i8) {
      bf16x8 wv8 = *(const bf16x8*)(wl + (size_t)(d * 64 + i8 * 16 + jg) * 8);
      #pragma unroll
      for (int e = 0; e < 8; ++e) val[i8 * 8 + e] += qd * bf2f(wv8[e]);
    }
  }

  float s = 0.f, ss = 0.f;
  #pragma unroll
  for (int i = 0; i < 32; ++i) { s += val[i]; ss += val[i] * val[i]; }
  #pragma unroll
  for (int m = 1; m < 16; m <<= 1) { s += __shfl_xor(s, m, 16); ss += __shfl_xor(ss, m, 16); }
  float mu = s * (1.0f / 512.0f);
  float var = ss * (1.0f / 512.0f) - mu * mu;
  float rstd = rsqrtf(var + 1e-6f);

  float* orow = out + ((size_t)(bb * SL + l)) * DM + jg * 32;
  const float* gam = gamma + jg * 32;
  const float* bet = beta + jg * 32;
  #pragma unroll
  for (int i = 0; i < 32; ++i)
    orow[i] = (val[i] - mu) * rstd * gam[i] + bet[i];
}

extern "C" void kernel_launch(void* const* d_in, const int* in_sizes, int n_in,
                              void* d_out, int out_size, void* d_ws, size_t ws_size,
                              hipStream_t stream) {
  (void)in_sizes; (void)n_in; (void)out_size; (void)ws_size;
  const float* q     = (const float*)d_in[0];
  const float* k     = (const float*)d_in[1];
  const float* v     = (const float*)d_in[2];
  const float* w_qs  = (const float*)d_in[3];
  const float* w_ks  = (const float*)d_in[4];
  const float* w_vs  = (const float*)d_in[5];
  const float* w_sk  = (const float*)d_in[6];
  const float* w_fc  = (const float*)d_in[7];
  const float* gamma = (const float*)d_in[8];
  const float* beta  = (const float*)d_in[9];

  float* out  = (float*)d_out;
  float* attn = out + (size_t)NB * SL * DM;   // 2,097,152 floats

  char* wsb = (char*)d_ws;                    // ~35.3 MB
  ushort* qb   = (ushort*)(wsb + 0);
  ushort* kb   = (ushort*)(wsb + 4194304);
  ushort* vb   = (ushort*)(wsb + 8388608);
  ushort* wqT  = (ushort*)(wsb + 12582912);
  ushort* wkT  = (ushort*)(wsb + 13107200);
  ushort* wvT  = (ushort*)(wsb + 13631488);
  ushort* wfcb = (ushort*)(wsb + 14155776);
  ushort* Qh   = (ushort*)(wsb + 14221312);
  ushort* Kh   = (ushort*)(wsb + 18415616);
  ushort* VhT  = (ushort*)(wsb + 22609920);
  float*  O    = (float*)(wsb + 26804224);
  float*  part = (float*)(wsb + 35192832);
  float*  gbuf = (float*)(wsb + 35225600);

  k_cvt_all<<<dim3(2272), dim3(256), 0, stream>>>(q, k, v, qb, kb, vb,
                                                  w_qs, w_ks, w_vs, wqT, wkT, wvT,
                                                  w_fc, wfcb);
  k_proj<<<dim3(64, 8, 3), dim3(256), 0, stream>>>(qb, kb, vb, wqT, wkT, wvT, Qh, Kh, VhT);
  k_attn<<<dim3(2048), dim3(256), 0, stream>>>(Qh, Kh, VhT, attn, O);
  k_reduce<<<dim3(32, 4), dim3(256), 0, stream>>>(O, part);
  k_gate<<<dim3(4), dim3(256), 0, stream>>>(part, w_sk, gbuf);
  k_final<<<dim3(64, 4), dim3(256), 0, stream>>>(O, gbuf, wfcb, q, gamma, beta, out);
}

// Round 9
// 164.767 us; speedup vs baseline: 1.2285x; 1.0019x over previous
//
#include <hip/hip_runtime.h>
#include <hip/hip_bf16.h>
#include <cstdint>

#define NH 8
#define DM 512
#define DH 64
#define NB 4
#define SL 1024

typedef __attribute__((ext_vector_type(8))) short bf16x8;
typedef __attribute__((ext_vector_type(4))) float f32x4;

static __device__ __forceinline__ float bf2f(short s) {
  union { unsigned int u; float f; } c;
  c.u = ((unsigned int)(unsigned short)s) << 16;
  return c.f;
}
static __device__ __forceinline__ unsigned short f2bfbits(float f) {
  union { float f; unsigned int u; } c; c.f = f;
  unsigned int lsb = (c.u >> 16) & 1u;
  unsigned int r = c.u + 0x7fffu + lsb;   // RNE (inputs are finite/normal)
  return (unsigned short)(r >> 16);
}

// ---------- 1) merged converts: qkv fp32->bf16, W^T transpose, w_fc ----------
// blocks 0..2047: qkv; 2048..2239: W transpose (3x8x8); 2240..2271: w_fc
__global__ __launch_bounds__(256) void k_cvt_all(
    const float* __restrict__ q, const float* __restrict__ k, const float* __restrict__ v,
    ushort* __restrict__ qb, ushort* __restrict__ kb, ushort* __restrict__ vb,
    const float* __restrict__ w0, const float* __restrict__ w1, const float* __restrict__ w2,
    ushort* __restrict__ o0, ushort* __restrict__ o1, ushort* __restrict__ o2,
    const float* __restrict__ wfc, ushort* __restrict__ wfcb) {
  __shared__ ushort tile[64][65];
  int b = blockIdx.x, t = threadIdx.x;
  if (b < 2048) {
    int i = b * 256 + t;
    {
      float4 f = ((const float4*)q)[i];
      ushort4 r = { f2bfbits(f.x), f2bfbits(f.y), f2bfbits(f.z), f2bfbits(f.w) };
      *(ushort4*)(qb + 4 * i) = r;
    }
    {
      float4 f = ((const float4*)k)[i];
      ushort4 r = { f2bfbits(f.x), f2bfbits(f.y), f2bfbits(f.z), f2bfbits(f.w) };
      *(ushort4*)(kb + 4 * i) = r;
    }
    {
      float4 f = ((const float4*)v)[i];
      ushort4 r = { f2bfbits(f.x), f2bfbits(f.y), f2bfbits(f.z), f2bfbits(f.w) };
      *(ushort4*)(vb + 4 * i) = r;
    }
  } else if (b < 2240) {
    int idx = b - 2048;           // 0..191
    int z = idx >> 6, rem = idx & 63;
    int k0 = (rem & 7) * 64, n0 = (rem >> 3) * 64;
    const float* src = z == 0 ? w0 : (z == 1 ? w1 : w2);
    ushort* dst = z == 0 ? o0 : (z == 1 ? o1 : o2);
    #pragma unroll
    for (int i = 0; i < 16; ++i) {
      int lin = t + i * 256, r = lin >> 6, c = lin & 63;
      tile[r][c] = f2bfbits(src[(size_t)(k0 + r) * DM + n0 + c]);
    }
    __syncthreads();
    #pragma unroll
    for (int i = 0; i < 16; ++i) {
      int lin = t + i * 256, r = lin >> 6, c = lin & 63;
      dst[(size_t)(n0 + r) * DM + k0 + c] = tile[c][r];
    }
  } else {
    int i = (b - 2240) * 256 + t;   // 8192 float4 groups
    float4 f = ((const float4*)wfc)[i];
    ushort4 r = { f2bfbits(f.x), f2bfbits(f.y), f2bfbits(f.z), f2bfbits(f.w) };
    *(ushort4*)(wfcb + 4 * i) = r;
  }
}

// ---------- 4) projection GEMM: [4096,512]bf16 @ W^T -> heads ----------
// z=0: Q (scale log2e/8, out [B,H,L,64]); z=1: K; z=2: V (out [B,H,64,L] transposed)
__global__ __launch_bounds__(256) void k_proj(
    const ushort* __restrict__ qb, const ushort* __restrict__ kb, const ushort* __restrict__ vb,
    const ushort* __restrict__ wqT, const ushort* __restrict__ wkT, const ushort* __restrict__ wvT,
    ushort* __restrict__ Qh, ushort* __restrict__ Kh, ushort* __restrict__ VhT) {
  int z = blockIdx.z;
  const ushort* A = z == 0 ? qb : (z == 1 ? kb : vb);
  const ushort* W = z == 0 ? wqT : (z == 1 ? wkT : wvT);
  ushort* Out = z == 0 ? Qh : (z == 1 ? Kh : VhT);
  // Q pre-scaled by 1/sqrt(dk) * log2(e): attention runs in exp2 domain.
  float scale = z == 0 ? 0.125f * 1.44269504088896f : 1.0f;

  int wid = threadIdx.x >> 6, l = threadIdx.x & 63;
  int lr = l & 15, lg = l >> 4;
  int row0 = blockIdx.x * 64 + wid * 16;
  int col0 = blockIdx.y * 64;
  const ushort* Arow = A + (size_t)(row0 + lr) * DM + lg * 8;

  f32x4 acc0 = {0.f, 0.f, 0.f, 0.f}, acc1 = acc0, acc2 = acc0, acc3 = acc0;
  #pragma unroll 4
  for (int kt = 0; kt < 16; ++kt) {
    bf16x8 a = *(const bf16x8*)(Arow + kt * 32);
    bf16x8 b0 = *(const bf16x8*)(W + (size_t)(col0 + 0 * 16 + lr) * DM + kt * 32 + lg * 8);
    bf16x8 b1 = *(const bf16x8*)(W + (size_t)(col0 + 1 * 16 + lr) * DM + kt * 32 + lg * 8);
    bf16x8 b2 = *(const bf16x8*)(W + (size_t)(col0 + 2 * 16 + lr) * DM + kt * 32 + lg * 8);
    bf16x8 b3 = *(const bf16x8*)(W + (size_t)(col0 + 3 * 16 + lr) * DM + kt * 32 + lg * 8);
    acc0 = __builtin_amdgcn_mfma_f32_16x16x32_bf16(a, b0, acc0, 0, 0, 0);
    acc1 = __builtin_amdgcn_mfma_f32_16x16x32_bf16(a, b1, acc1, 0, 0, 0);
    acc2 = __builtin_amdgcn_mfma_f32_16x16x32_bf16(a, b2, acc2, 0, 0, 0);
    acc3 = __builtin_amdgcn_mfma_f32_16x16x32_bf16(a, b3, acc3, 0, 0, 0);
  }
  f32x4 accs[4] = {acc0, acc1, acc2, acc3};
  #pragma unroll
  for (int ct = 0; ct < 4; ++ct) {
    int gcol = col0 + ct * 16 + lr;
    int h = gcol >> 6, d = gcol & 63;
    #pragma unroll
    for (int r = 0; r < 4; ++r) {
      int grow = row0 + lg * 4 + r;
      int bb = grow >> 10, li = grow & 1023;
      float val = accs[ct][r] * scale;
      size_t addr;
      if (z == 2) addr = ((size_t)((bb * NH + h) * DH + d)) * SL + li;
      else        addr = ((size_t)((bb * NH + h) * SL + li)) * DH + d;
      Out[addr] = f2bfbits(val);
    }
  }
}

// ---------- 5) fused attention: 2 phases, 1 barrier ----------
// Swapped QK^T (mfma(K,Q): lane holds p for q=lane&15). No-max exp2 softmax:
// phase 1 writes UNNORMALIZED bf16 p to swizzled LDS, row sums in regs.
// Phase 2: V loads of each half issued before that half's stores (in-order
// vmcnt). Attn stores are NON-TEMPORAL: the 139 MB stream bypasses L2, so it
// neither evicts the K/V working set nor serializes on dirty writebacks.
__global__ __launch_bounds__(256, 4) void k_attn(
    const ushort* __restrict__ Qh, const ushort* __restrict__ Kh, const ushort* __restrict__ VhT,
    float* __restrict__ attn_out, float* __restrict__ O) {
  __shared__ __align__(16) ushort S[16 * 1024];   // 32 KB, byte ^= (q&7)<<4
  __shared__ float spart[4][16];                  // per-wave partial row sums
  char* Sb = (char*)S;

  int bid = blockIdx.x;             // 0..2047
  int xcd = bid & 7;
  int loc = bid >> 3;               // 0..255
  int bh  = xcd * 4 + (loc >> 6);   // 4 contiguous bh per XCD L2
  int rt  = loc & 63;
  int wid = threadIdx.x >> 6, l = threadIdx.x & 63;
  int lr = l & 15, g = l >> 4;
  int q0 = rt * 16;

  // Q fragment (B-operand of swapped QK^T): col=lane&15 -> q row
  const ushort* Qbase = Qh + ((size_t)(bh * SL + q0 + lr)) * DH + g * 8;
  bf16x8 bQ0 = *(const bf16x8*)(Qbase);
  bf16x8 bQ1 = *(const bf16x8*)(Qbase + 32);
  const ushort* Kbase = Kh + (size_t)bh * SL * DH + (size_t)lr * DH + g * 8;

  // ---- phase 1: QK^T, p=exp2(acc) unnormalized -> LDS; row-sum in reg ----
  float sacc = 0.f;
  #pragma unroll 2
  for (int ct = 0; ct < 16; ++ct) {
    int k0 = wid * 256 + ct * 16;
    const ushort* kp = Kbase + (size_t)k0 * DH;
    bf16x8 a0 = *(const bf16x8*)(kp);
    bf16x8 a1 = *(const bf16x8*)(kp + 32);
    f32x4 acc = {0.f, 0.f, 0.f, 0.f};
    acc = __builtin_amdgcn_mfma_f32_16x16x32_bf16(a0, bQ0, acc, 0, 0, 0);
    acc = __builtin_amdgcn_mfma_f32_16x16x32_bf16(a1, bQ1, acc, 0, 0, 0);
    // lane holds D[k=k0+4g+r][q=lr]
    float p0 = exp2f(acc[0]), p1 = exp2f(acc[1]);
    float p2 = exp2f(acc[2]), p3 = exp2f(acc[3]);
    sacc += (p0 + p1) + (p2 + p3);
    unsigned int pk0, pk1;
    asm("v_cvt_pk_bf16_f32 %0, %1, %2" : "=v"(pk0) : "v"(p0), "v"(p1));
    asm("v_cvt_pk_bf16_f32 %0, %1, %2" : "=v"(pk1) : "v"(p2), "v"(p3));
    uint2 w2 = { pk0, pk1 };                       // k = k0+4g..k0+4g+3, q = lr
    *(uint2*)(Sb + (((lr << 11) + ((k0 + 4 * g) << 1)) ^ ((lr & 7) << 4))) = w2;
  }
  // sum the 4 k-lane-groups sharing q=lr
  sacc += __shfl_xor(sacc, 16);
  sacc += __shfl_xor(sacc, 32);
  if (l < 16) spart[wid][l] = sacc;
  __syncthreads();

  const ushort* Vbase = VhT + (size_t)bh * DH * SL + (size_t)(wid * 16 + lr) * SL + g * 8;
  size_t attn_base = (size_t)bh * SL * SL + (size_t)q0 * SL;
  f32x4 accA = {0.f, 0.f, 0.f, 0.f}, accB = accA;
  bf16x8 va[16];

  // ---- half A: V loads 0..15 issued first, then MFMA ----
  #pragma unroll
  for (int kt = 0; kt < 16; ++kt) va[kt] = *(const bf16x8*)(Vbase + kt * 32);
  #pragma unroll
  for (int kt = 0; kt < 16; ++kt) {
    bf16x8 aP = *(const bf16x8*)(Sb + (((lr << 11) + ((kt * 32 + g * 8) << 1)) ^ ((lr & 7) << 4)));
    if (kt & 1) accB = __builtin_amdgcn_mfma_f32_16x16x32_bf16(aP, va[kt], accB, 0, 0, 0);
    else        accA = __builtin_amdgcn_mfma_f32_16x16x32_bf16(aP, va[kt], accA, 0, 0, 0);
  }
  // ---- half B: V loads 16..31 (BEFORE any store) ----
  #pragma unroll
  for (int kt = 0; kt < 16; ++kt) va[kt] = *(const bf16x8*)(Vbase + (16 + kt) * 32);
  // ---- attn stores, first half (rows wid*4+rr, cols 4l + 256*{0,1}) ----
  #pragma unroll
  for (int j = 0; j < 8; ++j) {
    int rr = j >> 1, i = j & 1;
    int r = wid * 4 + rr;
    float inv = 1.0f / (spart[0][r] + spart[1][r] + spart[2][r] + spart[3][r]);
    int c0 = 4 * l + 256 * i;
    uint2 u = *(uint2*)(Sb + (((r << 11) + (c0 << 1)) ^ ((r & 7) << 4)));
    f32x4 pv;
    pv[0] = bf2f((short)(u.x & 0xffff)) * inv;
    pv[1] = bf2f((short)(u.x >> 16)) * inv;
    pv[2] = bf2f((short)(u.y & 0xffff)) * inv;
    pv[3] = bf2f((short)(u.y >> 16)) * inv;
    __builtin_nontemporal_store(pv, (f32x4*)(attn_out + attn_base + (size_t)r * SL + c0));
  }
  // ---- MFMA half B (V already in regs; waits only on older loads) ----
  #pragma unroll
  for (int kt = 0; kt < 16; ++kt) {
    bf16x8 aP = *(const bf16x8*)(Sb + (((lr << 11) + (((16 + kt) * 32 + g * 8) << 1)) ^ ((lr & 7) << 4)));
    if (kt & 1) accB = __builtin_amdgcn_mfma_f32_16x16x32_bf16(aP, va[kt], accB, 0, 0, 0);
    else        accA = __builtin_amdgcn_mfma_f32_16x16x32_bf16(aP, va[kt], accA, 0, 0, 0);
  }
  // ---- attn stores, second half ----
  #pragma unroll
  for (int j = 0; j < 8; ++j) {
    int rr = j >> 1, i = 2 + (j & 1);
    int r = wid * 4 + rr;
    float inv = 1.0f / (spart[0][r] + spart[1][r] + spart[2][r] + spart[3][r]);
    int c0 = 4 * l + 256 * i;
    uint2 u = *(uint2*)(Sb + (((r << 11) + (c0 << 1)) ^ ((r & 7) << 4)));
    f32x4 pv;
    pv[0] = bf2f((short)(u.x & 0xffff)) * inv;
    pv[1] = bf2f((short)(u.x >> 16)) * inv;
    pv[2] = bf2f((short)(u.y & 0xffff)) * inv;
    pv[3] = bf2f((short)(u.y >> 16)) * inv;
    __builtin_nontemporal_store(pv, (f32x4*)(attn_out + attn_base + (size_t)r * SL + c0));
  }
  // ---- O store: D[q=4g+r][d=wid*16+lr], normalized (cached: re-read soon) ----
  f32x4 acc = accA;
  acc[0] += accB[0]; acc[1] += accB[1]; acc[2] += accB[2]; acc[3] += accB[3];
  #pragma unroll
  for (int r = 0; r < 4; ++r) {
    int qr = 4 * g + r;
    float inv = 1.0f / (spart[0][qr] + spart[1][qr] + spart[2][qr] + spart[3][qr]);
    O[((size_t)(bh * SL + q0 + qr)) * DH + wid * 16 + lr] = acc[r] * inv;
  }
}

// ---------- 6) partial reduce for s: partial[b][slab][d] ----------
__global__ __launch_bounds__(256) void k_reduce(const float* __restrict__ O, float* __restrict__ partial) {
  int slab = blockIdx.x, bb = blockIdx.y;
  int d = threadIdx.x & 63, sub = threadIdx.x >> 6;
  float s = 0.f;
  for (int h = 0; h < NH; ++h) {
    const float* base = O + ((size_t)((bb * NH + h) * SL + slab * 32 + sub * 8)) * DH + d;
    #pragma unroll
    for (int li = 0; li < 8; ++li) s += base[(size_t)li * DH];
  }
  __shared__ float red[4][64];
  red[sub][d] = s;
  __syncthreads();
  if (threadIdx.x < 64) {
    float t = red[0][d] + red[1][d] + red[2][d] + red[3][d];
    partial[(bb * 32 + slab) * 64 + d] = t;
  }
}

// ---------- 7) gate: s @ w_sk, softmax over heads ----------
__global__ __launch_bounds__(256) void k_gate(const float* __restrict__ partial,
                                              const float* __restrict__ wsk, float* __restrict__ g) {
  int bb = blockIdx.x;
  int t = threadIdx.x;
  __shared__ float red[4][64];
  __shared__ float sl[64];
  __shared__ float logit[512];
  int d = t & 63, q4 = t >> 6;
  float s = 0.f;
  for (int i = 0; i < 8; ++i) s += partial[(bb * 32 + q4 * 8 + i) * 64 + d];
  red[q4][d] = s;
  __syncthreads();
  if (t < 64) sl[t] = (red[0][t] + red[1][t] + red[2][t] + red[3][t]) * (1.0f / 1024.0f);
  __syncthreads();
  #pragma unroll
  for (int jj = 0; jj < 2; ++jj) {
    int j = t + jj * 256;
    float lg = 0.f;
    #pragma unroll 8
    for (int c = 0; c < 64; ++c) lg += sl[c] * wsk[c * DM + j];
    logit[j] = lg;
  }
  __syncthreads();
  if (t < 64) {
    float m = -1e30f;
    #pragma unroll
    for (int h = 0; h < NH; ++h) m = fmaxf(m, logit[h * 64 + t]);
    float sum = 0.f, e[NH];
    #pragma unroll
    for (int h = 0; h < NH; ++h) { e[h] = __expf(logit[h * 64 + t] - m); sum += e[h]; }
    float inv = 1.0f / sum;
    #pragma unroll
    for (int h = 0; h < NH; ++h) g[bb * DM + h * 64 + t] = e[h] * inv;
  }
}

// ---------- 8) gate O -> qo, qo @ w_fc + residual, LayerNorm ----------
__global__ __launch_bounds__(256) void k_final(
    const float* __restrict__ O, const float* __restrict__ g, const ushort* __restrict__ wfc,
    const float* __restrict__ q, const float* __restrict__ gamma, const float* __restrict__ beta,
    float* __restrict__ out) {
  __shared__ __align__(16) ushort wl[32768];   // w_fc bf16, 16B-chunk swizzled [d][i8][jg]
  __shared__ __align__(16) float qo[16][64];
  __shared__ __align__(16) float gl[512];
  int lt = blockIdx.x, bb = blockIdx.y;
  int t = threadIdx.x;

  gl[t] = g[bb * DM + t];
  gl[t + 256] = g[bb * DM + 256 + t];
  {
    int jg2 = t & 15, hi = t >> 4;
    #pragma unroll
    for (int m = 0; m < 16; ++m) {
      int di = m * 16 + hi;             // 0..255
      int d = di >> 2, i8 = di & 3;
      bf16x8 w8 = *(const bf16x8*)(wfc + d * DM + jg2 * 32 + i8 * 8);
      *(bf16x8*)(wl + (size_t)(d * 64 + i8 * 16 + jg2) * 8) = w8;
    }
  }
  __syncthreads();

  int r = t >> 4, jg = t & 15;
  int l = lt * 16 + r;
  {
    float4 acc; acc.x = acc.y = acc.z = acc.w = 0.f;
    #pragma unroll
    for (int h = 0; h < NH; ++h) {
      float4 ov = *(const float4*)(O + ((size_t)((bb * NH + h) * SL + l)) * DH + jg * 4);
      float4 gv = *(const float4*)(gl + h * 64 + jg * 4);
      acc.x += ov.x * gv.x; acc.y += ov.y * gv.y; acc.z += ov.z * gv.z; acc.w += ov.w * gv.w;
    }
    *(float4*)&qo[r][jg * 4] = acc;
  }
  __syncthreads();

  float val[32];
  const float* qrow = q + ((size_t)(bb * SL + l)) * DM + jg * 32;
  #pragma unroll
  for (int i4 = 0; i4 < 8; ++i4) *(float4*)&val[i4 * 4] = *(const float4*)(qrow + i4 * 4);

  for (int d = 0; d < 64; ++d) {
    float qd = qo[r][d];
    #pragma unroll
    for (int i8 = 0; i8 < 4; ++i8) {
      bf16x8 wv8 = *(const bf16x8*)(wl + (size_t)(d * 64 + i8 * 16 + jg) * 8);
      #pragma unroll
      for (int e = 0; e < 8; ++e) val[i8 * 8 + e] += qd * bf2f(wv8[e]);
    }
  }

  float s = 0.f, ss = 0.f;
  #pragma unroll
  for (int i = 0; i < 32; ++i) { s += val[i]; ss += val[i] * val[i]; }
  #pragma unroll
  for (int m = 1; m < 16; m <<= 1) { s += __shfl_xor(s, m, 16); ss += __shfl_xor(ss, m, 16); }
  float mu = s * (1.0f / 512.0f);
  float var = ss * (1.0f / 512.0f) - mu * mu;
  float rstd = rsqrtf(var + 1e-6f);

  float* orow = out + ((size_t)(bb * SL + l)) * DM + jg * 32;
  const float* gam = gamma + jg * 32;
  const float* bet = beta + jg * 32;
  #pragma unroll
  for (int i = 0; i < 32; ++i)
    orow[i] = (val[i] - mu) * rstd * gam[i] + bet[i];
}

extern "C" void kernel_launch(void* const* d_in, const int* in_sizes, int n_in,
                              void* d_out, int out_size, void* d_ws, size_t ws_size,
                              hipStream_t stream) {
  (void)in_sizes; (void)n_in; (void)out_size; (void)ws_size;
  const float* q     = (const float*)d_in[0];
  const float* k     = (const float*)d_in[1];
  const float* v     = (const float*)d_in[2];
  const float* w_qs  = (const float*)d_in[3];
  const float* w_ks  = (const float*)d_in[4];
  const float* w_vs  = (const float*)d_in[5];
  const float* w_sk  = (const float*)d_in[6];
  const float* w_fc  = (const float*)d_in[7];
  const float* gamma = (const float*)d_in[8];
  const float* beta  = (const float*)d_in[9];

  float* out  = (float*)d_out;
  float* attn = out + (size_t)NB * SL * DM;   // 2,097,152 floats

  char* wsb = (char*)d_ws;                    // ~35.3 MB
  ushort* qb   = (ushort*)(wsb + 0);
  ushort* kb   = (ushort*)(wsb + 4194304);
  ushort* vb   = (ushort*)(wsb + 8388608);
  ushort* wqT  = (ushort*)(wsb + 12582912);
  ushort* wkT  = (ushort*)(wsb + 13107200);
  ushort* wvT  = (ushort*)(wsb + 13631488);
  ushort* wfcb = (ushort*)(wsb + 14155776);
  ushort* Qh   = (ushort*)(wsb + 14221312);
  ushort* Kh   = (ushort*)(wsb + 18415616);
  ushort* VhT  = (ushort*)(wsb + 22609920);
  float*  O    = (float*)(wsb + 26804224);
  float*  part = (float*)(wsb + 35192832);
  float*  gbuf = (float*)(wsb + 35225600);

  k_cvt_all<<<dim3(2272), dim3(256), 0, stream>>>(q, k, v, qb, kb, vb,
                                                  w_qs, w_ks, w_vs, wqT, wkT, wvT,
                                                  w_fc, wfcb);
  k_proj<<<dim3(64, 8, 3), dim3(256), 0, stream>>>(qb, kb, vb, wqT, wkT, wvT, Qh, Kh, VhT);
  k_attn<<<dim3(2048), dim3(256), 0, stream>>>(Qh, Kh, VhT, attn, O);
  k_reduce<<<dim3(32, 4), dim3(256), 0, stream>>>(O, part);
  k_gate<<<dim3(4), dim3(256), 0, stream>>>(part, w_sk, gbuf);
  k_final<<<dim3(64, 4), dim3(256), 0, stream>>>(O, gbuf, wfcb, q, gamma, beta, out);
}

// Round 10
// 163.277 us; speedup vs baseline: 1.2397x; 1.0091x over previous
//
#include <hip/hip_runtime.h>
#include <hip/hip_bf16.h>
#include <cstdint>

#define NH 8
#define DM 512
#define DH 64
#define NB 4
#define SL 1024

typedef __attribute__((ext_vector_type(8))) short bf16x8;
typedef __attribute__((ext_vector_type(4))) float f32x4;

static __device__ __forceinline__ float bf2f(short s) {
  union { unsigned int u; float f; } c;
  c.u = ((unsigned int)(unsigned short)s) << 16;
  return c.f;
}
static __device__ __forceinline__ unsigned short f2bfbits(float f) {
  union { float f; unsigned int u; } c; c.f = f;
  unsigned int lsb = (c.u >> 16) & 1u;
  unsigned int r = c.u + 0x7fffu + lsb;   // RNE (inputs are finite/normal)
  return (unsigned short)(r >> 16);
}

// ---------- 1) merged converts: qkv fp32->bf16, W^T transpose, w_fc ----------
// blocks 0..2047: qkv; 2048..2239: W transpose (3x8x8); 2240..2271: w_fc
__global__ __launch_bounds__(256) void k_cvt_all(
    const float* __restrict__ q, const float* __restrict__ k, const float* __restrict__ v,
    ushort* __restrict__ qb, ushort* __restrict__ kb, ushort* __restrict__ vb,
    const float* __restrict__ w0, const float* __restrict__ w1, const float* __restrict__ w2,
    ushort* __restrict__ o0, ushort* __restrict__ o1, ushort* __restrict__ o2,
    const float* __restrict__ wfc, ushort* __restrict__ wfcb) {
  __shared__ ushort tile[64][65];
  int b = blockIdx.x, t = threadIdx.x;
  if (b < 2048) {
    int i = b * 256 + t;
    {
      float4 f = ((const float4*)q)[i];
      ushort4 r = { f2bfbits(f.x), f2bfbits(f.y), f2bfbits(f.z), f2bfbits(f.w) };
      *(ushort4*)(qb + 4 * i) = r;
    }
    {
      float4 f = ((const float4*)k)[i];
      ushort4 r = { f2bfbits(f.x), f2bfbits(f.y), f2bfbits(f.z), f2bfbits(f.w) };
      *(ushort4*)(kb + 4 * i) = r;
    }
    {
      float4 f = ((const float4*)v)[i];
      ushort4 r = { f2bfbits(f.x), f2bfbits(f.y), f2bfbits(f.z), f2bfbits(f.w) };
      *(ushort4*)(vb + 4 * i) = r;
    }
  } else if (b < 2240) {
    int idx = b - 2048;           // 0..191
    int z = idx >> 6, rem = idx & 63;
    int k0 = (rem & 7) * 64, n0 = (rem >> 3) * 64;
    const float* src = z == 0 ? w0 : (z == 1 ? w1 : w2);
    ushort* dst = z == 0 ? o0 : (z == 1 ? o1 : o2);
    #pragma unroll
    for (int i = 0; i < 16; ++i) {
      int lin = t + i * 256, r = lin >> 6, c = lin & 63;
      tile[r][c] = f2bfbits(src[(size_t)(k0 + r) * DM + n0 + c]);
    }
    __syncthreads();
    #pragma unroll
    for (int i = 0; i < 16; ++i) {
      int lin = t + i * 256, r = lin >> 6, c = lin & 63;
      dst[(size_t)(n0 + r) * DM + k0 + c] = tile[c][r];
    }
  } else {
    int i = (b - 2240) * 256 + t;   // 8192 float4 groups
    float4 f = ((const float4*)wfc)[i];
    ushort4 r = { f2bfbits(f.x), f2bfbits(f.y), f2bfbits(f.z), f2bfbits(f.w) };
    *(ushort4*)(wfcb + 4 * i) = r;
  }
}

// ---------- 4) projection GEMM: [4096,512]bf16 @ W^T -> heads ----------
// z=0: Q (scale log2e/8, out [B,H,L,64]); z=1: K; z=2: V (out [B,H,64,L] transposed)
__global__ __launch_bounds__(256) void k_proj(
    const ushort* __restrict__ qb, const ushort* __restrict__ kb, const ushort* __restrict__ vb,
    const ushort* __restrict__ wqT, const ushort* __restrict__ wkT, const ushort* __restrict__ wvT,
    ushort* __restrict__ Qh, ushort* __restrict__ Kh, ushort* __restrict__ VhT) {
  int z = blockIdx.z;
  const ushort* A = z == 0 ? qb : (z == 1 ? kb : vb);
  const ushort* W = z == 0 ? wqT : (z == 1 ? wkT : wvT);
  ushort* Out = z == 0 ? Qh : (z == 1 ? Kh : VhT);
  // Q pre-scaled by 1/sqrt(dk) * log2(e): attention runs in exp2 domain.
  float scale = z == 0 ? 0.125f * 1.44269504088896f : 1.0f;

  int wid = threadIdx.x >> 6, l = threadIdx.x & 63;
  int lr = l & 15, lg = l >> 4;
  int row0 = blockIdx.x * 64 + wid * 16;
  int col0 = blockIdx.y * 64;
  const ushort* Arow = A + (size_t)(row0 + lr) * DM + lg * 8;

  f32x4 acc0 = {0.f, 0.f, 0.f, 0.f}, acc1 = acc0, acc2 = acc0, acc3 = acc0;
  #pragma unroll 4
  for (int kt = 0; kt < 16; ++kt) {
    bf16x8 a = *(const bf16x8*)(Arow + kt * 32);
    bf16x8 b0 = *(const bf16x8*)(W + (size_t)(col0 + 0 * 16 + lr) * DM + kt * 32 + lg * 8);
    bf16x8 b1 = *(const bf16x8*)(W + (size_t)(col0 + 1 * 16 + lr) * DM + kt * 32 + lg * 8);
    bf16x8 b2 = *(const bf16x8*)(W + (size_t)(col0 + 2 * 16 + lr) * DM + kt * 32 + lg * 8);
    bf16x8 b3 = *(const bf16x8*)(W + (size_t)(col0 + 3 * 16 + lr) * DM + kt * 32 + lg * 8);
    acc0 = __builtin_amdgcn_mfma_f32_16x16x32_bf16(a, b0, acc0, 0, 0, 0);
    acc1 = __builtin_amdgcn_mfma_f32_16x16x32_bf16(a, b1, acc1, 0, 0, 0);
    acc2 = __builtin_amdgcn_mfma_f32_16x16x32_bf16(a, b2, acc2, 0, 0, 0);
    acc3 = __builtin_amdgcn_mfma_f32_16x16x32_bf16(a, b3, acc3, 0, 0, 0);
  }
  f32x4 accs[4] = {acc0, acc1, acc2, acc3};
  #pragma unroll
  for (int ct = 0; ct < 4; ++ct) {
    int gcol = col0 + ct * 16 + lr;
    int h = gcol >> 6, d = gcol & 63;
    #pragma unroll
    for (int r = 0; r < 4; ++r) {
      int grow = row0 + lg * 4 + r;
      int bb = grow >> 10, li = grow & 1023;
      float val = accs[ct][r] * scale;
      size_t addr;
      if (z == 2) addr = ((size_t)((bb * NH + h) * DH + d)) * SL + li;
      else        addr = ((size_t)((bb * NH + h) * SL + li)) * DH + d;
      Out[addr] = f2bfbits(val);
    }
  }
}

// ---------- 5) fused attention: 2 phases, 1 barrier ----------
// Swapped QK^T (mfma(K,Q): lane holds p for q=lane&15). No-max exp2 softmax:
// phase 1 writes UNNORMALIZED bf16 p to swizzled LDS, row sums in regs, with
// DISTANCE-2 ping-pong K prefetch (L2 latency hidden under 2 iters of work).
// Phase 2: V loads of each half issued before that half's attn stores.
__global__ __launch_bounds__(256, 4) void k_attn(
    const ushort* __restrict__ Qh, const ushort* __restrict__ Kh, const ushort* __restrict__ VhT,
    float* __restrict__ attn_out, float* __restrict__ O) {
  __shared__ __align__(16) ushort S[16 * 1024];   // 32 KB, byte ^= (q&7)<<4
  __shared__ float spart[4][16];                  // per-wave partial row sums
  char* Sb = (char*)S;

  int bid = blockIdx.x;             // 0..2047
  int xcd = bid & 7;
  int loc = bid >> 3;               // 0..255
  int bh  = xcd * 4 + (loc >> 6);   // 4 contiguous bh per XCD L2
  int rt  = loc & 63;
  int wid = threadIdx.x >> 6, l = threadIdx.x & 63;
  int lr = l & 15, g = l >> 4;
  int q0 = rt * 16;

  // Q fragment (B-operand of swapped QK^T): col=lane&15 -> q row
  const ushort* Qbase = Qh + ((size_t)(bh * SL + q0 + lr)) * DH + g * 8;
  bf16x8 bQ0 = *(const bf16x8*)(Qbase);
  bf16x8 bQ1 = *(const bf16x8*)(Qbase + 32);
  const ushort* Kbase = Kh + (size_t)bh * SL * DH + (size_t)lr * DH + g * 8;

  // ---- phase 1: QK^T with distance-2 K prefetch ----
  float sacc = 0.f;
  const ushort* kp0 = Kbase + (size_t)(wid * 256) * DH;
  bf16x8 ka0 = *(const bf16x8*)(kp0);
  bf16x8 ka1 = *(const bf16x8*)(kp0 + 32);
  bf16x8 kb0 = *(const bf16x8*)(kp0 + 16 * DH);
  bf16x8 kb1 = *(const bf16x8*)(kp0 + 16 * DH + 32);
  #pragma unroll
  for (int ct = 0; ct < 16; ++ct) {
    bf16x8 c0 = (ct & 1) ? kb0 : ka0;
    bf16x8 c1 = (ct & 1) ? kb1 : ka1;
    if (ct < 14) {
      const ushort* kn = Kbase + (size_t)(wid * 256 + (ct + 2) * 16) * DH;
      if (ct & 1) { kb0 = *(const bf16x8*)(kn); kb1 = *(const bf16x8*)(kn + 32); }
      else        { ka0 = *(const bf16x8*)(kn); ka1 = *(const bf16x8*)(kn + 32); }
    }
    f32x4 acc = {0.f, 0.f, 0.f, 0.f};
    acc = __builtin_amdgcn_mfma_f32_16x16x32_bf16(c0, bQ0, acc, 0, 0, 0);
    acc = __builtin_amdgcn_mfma_f32_16x16x32_bf16(c1, bQ1, acc, 0, 0, 0);
    // lane holds D[k=k0+4g+r][q=lr]
    int k0 = wid * 256 + ct * 16;
    float p0 = exp2f(acc[0]), p1 = exp2f(acc[1]);
    float p2 = exp2f(acc[2]), p3 = exp2f(acc[3]);
    sacc += (p0 + p1) + (p2 + p3);
    unsigned int pk0, pk1;
    asm("v_cvt_pk_bf16_f32 %0, %1, %2" : "=v"(pk0) : "v"(p0), "v"(p1));
    asm("v_cvt_pk_bf16_f32 %0, %1, %2" : "=v"(pk1) : "v"(p2), "v"(p3));
    uint2 w2 = { pk0, pk1 };                       // k = k0+4g..k0+4g+3, q = lr
    *(uint2*)(Sb + (((lr << 11) + ((k0 + 4 * g) << 1)) ^ ((lr & 7) << 4))) = w2;
  }
  // sum the 4 k-lane-groups sharing q=lr
  sacc += __shfl_xor(sacc, 16);
  sacc += __shfl_xor(sacc, 32);
  if (l < 16) spart[wid][l] = sacc;
  __syncthreads();

  const ushort* Vbase = VhT + (size_t)bh * DH * SL + (size_t)(wid * 16 + lr) * SL + g * 8;
  size_t attn_base = (size_t)bh * SL * SL + (size_t)q0 * SL;
  f32x4 accA = {0.f, 0.f, 0.f, 0.f}, accB = accA;
  bf16x8 va[16];

  // ---- half A: V loads 0..15 issued first, then MFMA ----
  #pragma unroll
  for (int kt = 0; kt < 16; ++kt) va[kt] = *(const bf16x8*)(Vbase + kt * 32);
  #pragma unroll
  for (int kt = 0; kt < 16; ++kt) {
    bf16x8 aP = *(const bf16x8*)(Sb + (((lr << 11) + ((kt * 32 + g * 8) << 1)) ^ ((lr & 7) << 4)));
    if (kt & 1) accB = __builtin_amdgcn_mfma_f32_16x16x32_bf16(aP, va[kt], accB, 0, 0, 0);
    else        accA = __builtin_amdgcn_mfma_f32_16x16x32_bf16(aP, va[kt], accA, 0, 0, 0);
  }
  // ---- half B: V loads 16..31 (BEFORE any store) ----
  #pragma unroll
  for (int kt = 0; kt < 16; ++kt) va[kt] = *(const bf16x8*)(Vbase + (16 + kt) * 32);
  // ---- attn stores, first half (rows wid*4+rr, cols 4l + 256*{0,1}) ----
  #pragma unroll
  for (int j = 0; j < 8; ++j) {
    int rr = j >> 1, i = j & 1;
    int r = wid * 4 + rr;
    float inv = 1.0f / (spart[0][r] + spart[1][r] + spart[2][r] + spart[3][r]);
    int c0 = 4 * l + 256 * i;
    uint2 u = *(uint2*)(Sb + (((r << 11) + (c0 << 1)) ^ ((r & 7) << 4)));
    f32x4 pv;
    pv[0] = bf2f((short)(u.x & 0xffff)) * inv;
    pv[1] = bf2f((short)(u.x >> 16)) * inv;
    pv[2] = bf2f((short)(u.y & 0xffff)) * inv;
    pv[3] = bf2f((short)(u.y >> 16)) * inv;
    __builtin_nontemporal_store(pv, (f32x4*)(attn_out + attn_base + (size_t)r * SL + c0));
  }
  // ---- MFMA half B (V already in regs; waits only on older loads) ----
  #pragma unroll
  for (int kt = 0; kt < 16; ++kt) {
    bf16x8 aP = *(const bf16x8*)(Sb + (((lr << 11) + (((16 + kt) * 32 + g * 8) << 1)) ^ ((lr & 7) << 4)));
    if (kt & 1) accB = __builtin_amdgcn_mfma_f32_16x16x32_bf16(aP, va[kt], accB, 0, 0, 0);
    else        accA = __builtin_amdgcn_mfma_f32_16x16x32_bf16(aP, va[kt], accA, 0, 0, 0);
  }
  // ---- attn stores, second half ----
  #pragma unroll
  for (int j = 0; j < 8; ++j) {
    int rr = j >> 1, i = 2 + (j & 1);
    int r = wid * 4 + rr;
    float inv = 1.0f / (spart[0][r] + spart[1][r] + spart[2][r] + spart[3][r]);
    int c0 = 4 * l + 256 * i;
    uint2 u = *(uint2*)(Sb + (((r << 11) + (c0 << 1)) ^ ((r & 7) << 4)));
    f32x4 pv;
    pv[0] = bf2f((short)(u.x & 0xffff)) * inv;
    pv[1] = bf2f((short)(u.x >> 16)) * inv;
    pv[2] = bf2f((short)(u.y & 0xffff)) * inv;
    pv[3] = bf2f((short)(u.y >> 16)) * inv;
    __builtin_nontemporal_store(pv, (f32x4*)(attn_out + attn_base + (size_t)r * SL + c0));
  }
  // ---- O store: D[q=4g+r][d=wid*16+lr], normalized (cached: re-read soon) ----
  f32x4 acc = accA;
  acc[0] += accB[0]; acc[1] += accB[1]; acc[2] += accB[2]; acc[3] += accB[3];
  #pragma unroll
  for (int r = 0; r < 4; ++r) {
    int qr = 4 * g + r;
    float inv = 1.0f / (spart[0][qr] + spart[1][qr] + spart[2][qr] + spart[3][qr]);
    O[((size_t)(bh * SL + q0 + qr)) * DH + wid * 16 + lr] = acc[r] * inv;
  }
}

// ---------- 6) partial reduce for s: partial[b][slab16][d], 256 blocks ----------
__global__ __launch_bounds__(256) void k_reduce(const float* __restrict__ O, float* __restrict__ partial) {
  int slab = blockIdx.x, bb = blockIdx.y;   // slab: 0..63, 16 rows each
  int d = threadIdx.x & 63, sub = threadIdx.x >> 6;
  float s = 0.f;
  for (int h = 0; h < NH; ++h) {
    const float* base = O + ((size_t)((bb * NH + h) * SL + slab * 16 + sub * 4)) * DH + d;
    #pragma unroll
    for (int li = 0; li < 4; ++li) s += base[(size_t)li * DH];
  }
  __shared__ float red[4][64];
  red[sub][d] = s;
  __syncthreads();
  if (threadIdx.x < 64) {
    float t = red[0][d] + red[1][d] + red[2][d] + red[3][d];
    partial[(bb * 64 + slab) * 64 + d] = t;
  }
}

// ---------- 7) gate: s @ w_sk, softmax over heads ----------
__global__ __launch_bounds__(256) void k_gate(const float* __restrict__ partial,
                                              const float* __restrict__ wsk, float* __restrict__ g) {
  int bb = blockIdx.x;
  int t = threadIdx.x;
  __shared__ float red[4][64];
  __shared__ float sl[64];
  __shared__ float logit[512];
  int d = t & 63, q4 = t >> 6;
  float s = 0.f;
  for (int i = 0; i < 16; ++i) s += partial[(bb * 64 + q4 * 16 + i) * 64 + d];
  red[q4][d] = s;
  __syncthreads();
  if (t < 64) sl[t] = (red[0][t] + red[1][t] + red[2][t] + red[3][t]) * (1.0f / 1024.0f);
  __syncthreads();
  #pragma unroll
  for (int jj = 0; jj < 2; ++jj) {
    int j = t + jj * 256;
    float lg = 0.f;
    #pragma unroll 8
    for (int c = 0; c < 64; ++c) lg += sl[c] * wsk[c * DM + j];
    logit[j] = lg;
  }
  __syncthreads();
  if (t < 64) {
    float m = -1e30f;
    #pragma unroll
    for (int h = 0; h < NH; ++h) m = fmaxf(m, logit[h * 64 + t]);
    float sum = 0.f, e[NH];
    #pragma unroll
    for (int h = 0; h < NH; ++h) { e[h] = __expf(logit[h * 64 + t] - m); sum += e[h]; }
    float inv = 1.0f / sum;
    #pragma unroll
    for (int h = 0; h < NH; ++h) g[bb * DM + h * 64 + t] = e[h] * inv;
  }
}

// ---------- 8) gate O -> qo, qo @ w_fc + residual, LayerNorm ----------
__global__ __launch_bounds__(256) void k_final(
    const float* __restrict__ O, const float* __restrict__ g, const ushort* __restrict__ wfc,
    const float* __restrict__ q, const float* __restrict__ gamma, const float* __restrict__ beta,
    float* __restrict__ out) {
  __shared__ __align__(16) ushort wl[32768];   // w_fc bf16, 16B-chunk swizzled [d][i8][jg]
  __shared__ __align__(16) float qo[16][64];
  __shared__ __align__(16) float gl[512];
  int lt = blockIdx.x, bb = blockIdx.y;
  int t = threadIdx.x;

  gl[t] = g[bb * DM + t];
  gl[t + 256] = g[bb * DM + 256 + t];
  {
    int jg2 = t & 15, hi = t >> 4;
    #pragma unroll
    for (int m = 0; m < 16; ++m) {
      int di = m * 16 + hi;             // 0..255
      int d = di >> 2, i8 = di & 3;
      bf16x8 w8 = *(const bf16x8*)(wfc + d * DM + jg2 * 32 + i8 * 8);
      *(bf16x8*)(wl + (size_t)(d * 64 + i8 * 16 + jg2) * 8) = w8;
    }
  }
  __syncthreads();

  int r = t >> 4, jg = t & 15;
  int l = lt * 16 + r;
  {
    float4 acc; acc.x = acc.y = acc.z = acc.w = 0.f;
    #pragma unroll
    for (int h = 0; h < NH; ++h) {
      float4 ov = *(const float4*)(O + ((size_t)((bb * NH + h) * SL + l)) * DH + jg * 4);
      float4 gv = *(const float4*)(gl + h * 64 + jg * 4);
      acc.x += ov.x * gv.x; acc.y += ov.y * gv.y; acc.z += ov.z * gv.z; acc.w += ov.w * gv.w;
    }
    *(float4*)&qo[r][jg * 4] = acc;
  }
  __syncthreads();

  float val[32];
  const float* qrow = q + ((size_t)(bb * SL + l)) * DM + jg * 32;
  #pragma unroll
  for (int i4 = 0; i4 < 8; ++i4) *(float4*)&val[i4 * 4] = *(const float4*)(qrow + i4 * 4);

  for (int d = 0; d < 64; ++d) {
    float qd = qo[r][d];
    #pragma unroll
    for (int i8 = 0; i8 < 4; ++i8) {
      bf16x8 wv8 = *(const bf16x8*)(wl + (size_t)(d * 64 + i8 * 16 + jg) * 8);
      #pragma unroll
      for (int e = 0; e < 8; ++e) val[i8 * 8 + e] += qd * bf2f(wv8[e]);
    }
  }

  float s = 0.f, ss = 0.f;
  #pragma unroll
  for (int i = 0; i < 32; ++i) { s += val[i]; ss += val[i] * val[i]; }
  #pragma unroll
  for (int m = 1; m < 16; m <<= 1) { s += __shfl_xor(s, m, 16); ss += __shfl_xor(ss, m, 16); }
  float mu = s * (1.0f / 512.0f);
  float var = ss * (1.0f / 512.0f) - mu * mu;
  float rstd = rsqrtf(var + 1e-6f);

  float* orow = out + ((size_t)(bb * SL + l)) * DM + jg * 32;
  const float* gam = gamma + jg * 32;
  const float* bet = beta + jg * 32;
  #pragma unroll
  for (int i = 0; i < 32; ++i)
    orow[i] = (val[i] - mu) * rstd * gam[i] + bet[i];
}

extern "C" void kernel_launch(void* const* d_in, const int* in_sizes, int n_in,
                              void* d_out, int out_size, void* d_ws, size_t ws_size,
                              hipStream_t stream) {
  (void)in_sizes; (void)n_in; (void)out_size; (void)ws_size;
  const float* q     = (const float*)d_in[0];
  const float* k     = (const float*)d_in[1];
  const float* v     = (const float*)d_in[2];
  const float* w_qs  = (const float*)d_in[3];
  const float* w_ks  = (const float*)d_in[4];
  const float* w_vs  = (const float*)d_in[5];
  const float* w_sk  = (const float*)d_in[6];
  const float* w_fc  = (const float*)d_in[7];
  const float* gamma = (const float*)d_in[8];
  const float* beta  = (const float*)d_in[9];

  float* out  = (float*)d_out;
  float* attn = out + (size_t)NB * SL * DM;   // 2,097,152 floats

  char* wsb = (char*)d_ws;                    // ~35.3 MB
  ushort* qb   = (ushort*)(wsb + 0);
  ushort* kb   = (ushort*)(wsb + 4194304);
  ushort* vb   = (ushort*)(wsb + 8388608);
  ushort* wqT  = (ushort*)(wsb + 12582912);
  ushort* wkT  = (ushort*)(wsb + 13107200);
  ushort* wvT  = (ushort*)(wsb + 13631488);
  ushort* wfcb = (ushort*)(wsb + 14155776);
  ushort* Qh   = (ushort*)(wsb + 14221312);
  ushort* Kh   = (ushort*)(wsb + 18415616);
  ushort* VhT  = (ushort*)(wsb + 22609920);
  float*  O    = (float*)(wsb + 26804224);
  // part (4b*64slab*64d = 64 KB) and gbuf (8 KB) overlay dead qb region
  // (qb is consumed by k_proj, which completes before k_reduce runs).
  float*  part = (float*)(wsb + 0);
  float*  gbuf = (float*)(wsb + 65536);

  k_cvt_all<<<dim3(2272), dim3(256), 0, stream>>>(q, k, v, qb, kb, vb,
                                                  w_qs, w_ks, w_vs, wqT, wkT, wvT,
                                                  w_fc, wfcb);
  k_proj<<<dim3(64, 8, 3), dim3(256), 0, stream>>>(qb, kb, vb, wqT, wkT, wvT, Qh, Kh, VhT);
  k_attn<<<dim3(2048), dim3(256), 0, stream>>>(Qh, Kh, VhT, attn, O);
  k_reduce<<<dim3(64, 4), dim3(256), 0, stream>>>(O, part);
  k_gate<<<dim3(4), dim3(256), 0, stream>>>(part, w_sk, gbuf);
  k_final<<<dim3(64, 4), dim3(256), 0, stream>>>(O, gbuf, wfcb, q, gamma, beta, out);
}